// Round 19
// baseline (334.063 us; speedup 1.0000x reference)
//
#include <hip/hip_runtime.h>

// ComplexAttention: B=4, S=2048, D=1024 -> single-head attention, head_dim 2048:
// Q/K/V = X@W^T+b ; S = Q@K^T/32 ; P = softmax(S) ; O = P@V ; out = O@Wo^T + bo.
// R19 = R18 with the MFMA shape swapped 16x16x32 -> 32x32x16 (+15% ubench ceiling:
// 2382 vs 2075 TF; half the MFMA instructions).  LDS traffic byte-identical; A/B
// frag = row lane&31, k=(lane>>5)*8+e (contiguous 16B, symmetric to the verified
// 16x16 pattern); C/D layout col=lane&31, row=(reg&3)+8*(reg>>2)+4*(lane>>5)
// (m74/m101 HW-verified).  Per-wave 128x64 = 4x2 of 32x32; acc f32x16[4][NH].
// Schedule/staging/swizzle = R15/R16 proven (1 barrier/K-tile, same-phase reads).

typedef short  bf16x8 __attribute__((ext_vector_type(8)));
typedef _Float16 f16x8 __attribute__((ext_vector_type(8)));
typedef float  f32x16 __attribute__((ext_vector_type(16)));
typedef unsigned short u16;

typedef __attribute__((address_space(3))) void       lds_void;
typedef const __attribute__((address_space(1))) void g_void;

__device__ __forceinline__ u16 f2bf(float f) {
  union { float f; unsigned u; } v; v.f = f;
  unsigned r = v.u + 0x7FFFu + ((v.u >> 16) & 1u);   // round-to-nearest-even
  return (u16)(r >> 16);
}
__device__ __forceinline__ u16 f2h(float f) {
  union { _Float16 h; u16 u; } v; v.h = (_Float16)f;
  return v.u;
}
__device__ __forceinline__ float h2f(u16 u) {
  union { u16 u; _Float16 h; } v; v.u = u;
  return (float)v.h;
}

// ------------- fp32 -> bf16 convert, ALL tensors in one launch -------------
__global__ __launch_bounds__(256) void cvt_all(
    const float* __restrict__ X,  const float* __restrict__ Wq,
    const float* __restrict__ Wk, const float* __restrict__ Wv,
    const float* __restrict__ Wo, u16* __restrict__ Xb, u16* __restrict__ Wqb,
    u16* __restrict__ Wkb, u16* __restrict__ Wvb, u16* __restrict__ Wob) {
  const int bid = blockIdx.x;
  const float* in; u16* out; int lb;
  if (bid < 8192) { in = X; out = Xb; lb = bid; }
  else {
    const int r = bid - 8192, s = r >> 11; lb = r & 2047;
    in  = (s == 0) ? Wq  : (s == 1) ? Wk  : (s == 2) ? Wv  : Wo;
    out = (s == 0) ? Wqb : (s == 1) ? Wkb : (s == 2) ? Wvb : Wob;
  }
  const int i = lb * 256 + threadIdx.x;
  const float4 v = ((const float4*)in)[i];
  union { u16 us[4]; unsigned long long ll; } u;
  u.us[0] = f2bf(v.x); u.us[1] = f2bf(v.y); u.us[2] = f2bf(v.z); u.us[3] = f2bf(v.w);
  ((unsigned long long*)out)[i] = u.ll;
}

// ---------------- 256x(NH*128) NT GEMM, 32x32x16 MFMA ----------------
// C[m,n] = alpha * sum_k A[m,k]*B[n,k] (+ bias[n]).  A,B 16-bit row-major (K contig).
// CMODE: 0=fp32 C, 1=bf16 C, 2=fp16 transposed-V Vt[b][n][t], 3=fp16 C.
// FT: 0=bf16 MFMA, 1=fp16 MFMA.  512 thr = 8 waves (2M x 4N); per-wave 128x64
// (NH=2) or 128x32 (NH=1) as 4x(NH) 32x32 tiles; BK=64 = 4 k-slices of 16.
// LDS identical to R15: A [2][256][64]u16 @0, B [2][..][64] @32768; XOR swizzle.
// Safety (R11/R15, ref-passed): per K-tile segment {reads+MMs; stage other buf;
// own vmcnt(0); BAR}.
template<int CMODE, bool BIAS, int NH, int FT>
__global__ __launch_bounds__(512, 2) void gemmK(const u16* __restrict__ A,
                                                const u16* __restrict__ B,
                                                void* __restrict__ Cv,
                                                const float* __restrict__ bias,
                                                int K, int lda, int ldb, int ldc,
                                                long bsA, long bsB, long bsC,
                                                float alpha)
{
  __shared__ u16 sm[65536];
  const int bz = blockIdx.z;
  const u16* Ab = A + (long)bz * bsA;
  const u16* Bb = B + (long)bz * bsB;
  const int m0 = blockIdx.y * 256, n0 = blockIdx.x * (NH * 128);
  const int tid = threadIdx.x, lane = tid & 63, w = tid >> 6;
  const int wmr = w >> 2, wnr = w & 3;
  const int c31 = lane & 31, hk = lane >> 5, l7 = lane & 7;

  f32x16 acc[4][NH] = {};
  bf16x8 afA[8], afB[8], bfA[4], bfB[4];

  // ---- hoisted LDS read bases: one per k-slice (XOR term depends on ks) ----
  const u16* aPk[4];
  const u16* bPk[4];
#pragma unroll
  for (int ks = 0; ks < 4; ++ks) {
    const int swz = ((ks * 2 + hk) ^ l7) * 8;
    aPk[ks] = sm + (wmr * 128 + c31) * 64 + swz;
    bPk[ks] = sm + 32768 + (wnr * (NH * 32) + c31) * 64 + swz;
  }

// frag reads: dst[mi*4+ks] = A rows (wmr*128 + MH*64 + mi*32 + c31), k-slice ks
#define LDAf(dst, D, MH)                                                        \
  { _Pragma("unroll") for (int mi = 0; mi < 2; ++mi)                            \
    _Pragma("unroll") for (int ks = 0; ks < 4; ++ks)                            \
      dst[mi * 4 + ks] = *(const bf16x8*)(aPk[ks] + (D) * 16384 + (MH) * 4096 + mi * 2048); }
#define LDBf(dst, D, NI)                                                        \
  { _Pragma("unroll") for (int ks = 0; ks < 4; ++ks)                            \
      dst[ks] = *(const bf16x8*)(bPk[ks] + (D) * 16384 + (NI) * 2048); }

  // ---- staging (identical to R15): row rl = q*64 + w*8 + (lane>>3),
  //      pre-swizzled src col ((lane&7)^(lane>>3))*8 ----
  const int lrow = w * 8 + (lane >> 3);
  const int c8 = ((lane & 7) ^ (lane >> 3)) * 8;
  const long dA = (long)lda * 64, dB = (long)ldb * 64;
  const u16* pA00 = Ab + (long)(m0 + lrow) * lda + c8;
  const u16* pA01 = pA00 + dA;
  const u16* pA10 = pA00 + 2 * dA;
  const u16* pA11 = pA00 + 3 * dA;
  const u16* pB00 = Bb + (long)(n0 + lrow) * ldb + c8;
  const u16* pB01 = pB00 + dB;
  const u16* pB10 = pB00 + 2 * dB;                           // NH==2 only
  const u16* pB11 = pB00 + 3 * dB;
  u16* dstB = sm + w * 512;

#define STG(ptr, CONSTOFF)                                                      \
  __builtin_amdgcn_global_load_lds((g_void*)(ptr), (lds_void*)(dstB + (CONSTOFF)), 16, 0, 0);
#define STG_A(D) { STG(pA00, (D)*16384 + 0)        STG(pA01, (D)*16384 + 4096)  \
                   STG(pA10, (D)*16384 + 8192)     STG(pA11, (D)*16384 + 12288) \
                   pA00 += 64; pA01 += 64; pA10 += 64; pA11 += 64; }
#define STG_B2(D) { STG(pB00, 32768 + (D)*16384 + 0)    STG(pB01, 32768 + (D)*16384 + 4096)  \
                    STG(pB10, 32768 + (D)*16384 + 8192) STG(pB11, 32768 + (D)*16384 + 12288) \
                    pB00 += 64; pB01 += 64; pB10 += 64; pB11 += 64; }
#define STG_B1(D) { STG(pB00, 32768 + (D)*16384 + 0)    STG(pB01, 32768 + (D)*16384 + 4096)  \
                    pB00 += 64; pB01 += 64; }

  // 8 MFMA: 2 m-tiles (mb+0, mb+1) x 4 k-slices into column ni
  auto MM = [&](const bf16x8* af, const bf16x8* bf, int mb, int ni) {
    __builtin_amdgcn_s_setprio(1);
#pragma unroll
    for (int mi = 0; mi < 2; ++mi)
#pragma unroll
      for (int ks = 0; ks < 4; ++ks) {
        if constexpr (FT == 0)
          acc[mb + mi][ni] = __builtin_amdgcn_mfma_f32_32x32x16_bf16(
              af[mi * 4 + ks], bf[ks], acc[mb + mi][ni], 0, 0, 0);
        else
          acc[mb + mi][ni] = __builtin_amdgcn_mfma_f32_32x32x16_f16(
              __builtin_bit_cast(f16x8, af[mi * 4 + ks]),
              __builtin_bit_cast(f16x8, bf[ks]),
              acc[mb + mi][ni], 0, 0, 0);
      }
    __builtin_amdgcn_s_setprio(0);
  };

#define KTILE2(D, SEN)                                                          \
  { LDAf(afA, D, 0) LDBf(bfA, D, 0)                                             \
    if (SEN) { STG_A(D ^ 1) }                                                   \
    MM(afA, bfA, 0, 0);                                                         \
    LDBf(bfB, D, 1)                                                             \
    if (SEN) { STG_B2(D ^ 1) }                                                  \
    MM(afA, bfB, 0, 1);                                                         \
    LDAf(afB, D, 1)                                                             \
    MM(afB, bfB, 2, 1);                                                         \
    MM(afB, bfA, 2, 0);                                                         \
    asm volatile("s_waitcnt vmcnt(0)" ::: "memory");                            \
    asm volatile("s_barrier" ::: "memory"); }
#define KTILE1(D, SEN)                                                          \
  { LDAf(afA, D, 0) LDBf(bfA, D, 0)                                             \
    if (SEN) { STG_A(D ^ 1) }                                                   \
    MM(afA, bfA, 0, 0);                                                         \
    LDAf(afB, D, 1)                                                             \
    if (SEN) { STG_B1(D ^ 1) }                                                  \
    MM(afB, bfA, 2, 0);                                                         \
    asm volatile("s_waitcnt vmcnt(0)" ::: "memory");                            \
    asm volatile("s_barrier" ::: "memory"); }

  const int nt = K >> 6, niter = nt >> 1;

  STG_A(0)
  if constexpr (NH == 2) { STG_B2(0) } else { STG_B1(0) }
  asm volatile("s_waitcnt vmcnt(0)" ::: "memory");
  asm volatile("s_barrier" ::: "memory");

  for (int j = 0; j < niter; ++j) {
    const bool pre = (j + 1 < niter);
    if constexpr (NH == 2) {
      KTILE2(0, true)
      KTILE2(1, pre)
    } else {
      KTILE1(0, true)
      KTILE1(1, pre)
    }
  }

  // epilogue: 32x32 C/D layout col=lane&31, row=(reg&3)+8*(reg>>2)+4*(lane>>5)
  // (m74/m101 HW-verified)
  const int rowb = 4 * hk;
#pragma unroll
  for (int mi = 0; mi < 4; ++mi) {
#pragma unroll
    for (int ni = 0; ni < NH; ++ni) {
      const int mgb = m0 + wmr * 128 + mi * 32 + rowb;
      const int ng  = n0 + wnr * (NH * 32) + ni * 32 + c31;
      const float bvv = BIAS ? bias[ng] : 0.0f;
      if constexpr (CMODE == 2) {
        u16* Cc = (u16*)Cv;
#pragma unroll
        for (int g = 0; g < 4; ++g) {
          const int mg = mgb + 8 * g;
          const long bb = mg >> 11;
          const int  t  = mg & 2047;
          union { u16 us[4]; unsigned long long ll; } u;
#pragma unroll
          for (int r = 0; r < 4; ++r) u.us[r] = f2h(acc[mi][ni][g * 4 + r] * alpha + bvv);
          *(unsigned long long*)(Cc + bb * 4194304 + (long)ng * 2048 + t) = u.ll;
        }
      } else if constexpr (CMODE == 1 || CMODE == 3) {
        u16* Cc = (u16*)Cv + (long)bz * bsC;
#pragma unroll
        for (int g = 0; g < 4; ++g)
#pragma unroll
          for (int r = 0; r < 4; ++r) {
            const float x = acc[mi][ni][g * 4 + r] * alpha + bvv;
            Cc[(long)(mgb + 8 * g + r) * ldc + ng] = (CMODE == 1) ? f2bf(x) : f2h(x);
          }
      } else {
        float* Cf = (float*)Cv + (long)bz * bsC;
#pragma unroll
        for (int g = 0; g < 4; ++g)
#pragma unroll
          for (int r = 0; r < 4; ++r)
            Cf[(long)(mgb + 8 * g + r) * ldc + ng] = acc[mi][ni][g * 4 + r] * alpha + bvv;
      }
    }
  }
#undef LDAf
#undef LDBf
#undef STG
#undef STG_A
#undef STG_B2
#undef STG_B1
#undef KTILE2
#undef KTILE1
}

// ---------------- row softmax: fp16 scores row (2048) -> fp16 P ----------------
__global__ __launch_bounds__(256) void softmax_f16(const u16* __restrict__ Scb,
                                                   u16* __restrict__ Pb) {
  const int tid = threadIdx.x;
  const long row = blockIdx.x;
  union { int4 v; u16 us[8]; } u;
  u.v = ((const int4*)(Scb + row * 2048))[tid];
  float f[8];
#pragma unroll
  for (int j = 0; j < 8; ++j) f[j] = h2f(u.us[j]);
  float mx = f[0];
#pragma unroll
  for (int j = 1; j < 8; ++j) mx = fmaxf(mx, f[j]);
  __shared__ float red[8];
  const int lane = tid & 63, wid = tid >> 6;
#pragma unroll
  for (int off = 32; off; off >>= 1) mx = fmaxf(mx, __shfl_down(mx, off));
  if (!lane) red[wid] = mx;
  __syncthreads();
  mx = fmaxf(fmaxf(red[0], red[1]), fmaxf(red[2], red[3]));
  float e[8], s = 0.f;
#pragma unroll
  for (int j = 0; j < 8; ++j) { e[j] = __expf(f[j] - mx); s += e[j]; }
#pragma unroll
  for (int off = 32; off; off >>= 1) s += __shfl_down(s, off);
  if (!lane) red[4 + wid] = s;
  __syncthreads();
  s = red[4] + red[5] + red[6] + red[7];
  const float inv = 1.0f / s;
  union { u16 us[8]; int4 v; } o;
#pragma unroll
  for (int j = 0; j < 8; ++j) o.us[j] = f2h(e[j] * inv);
  ((int4*)(Pb + row * 2048))[tid] = o.v;
}

extern "C" void kernel_launch(void* const* d_in, const int* in_sizes, int n_in,
                              void* d_out, int out_size, void* d_ws, size_t ws_size,
                              hipStream_t stream) {
  const float* X  = (const float*)d_in[0];
  const float* Wq = (const float*)d_in[1];
  const float* bq = (const float*)d_in[2];
  const float* Wk = (const float*)d_in[3];
  const float* bk = (const float*)d_in[4];
  const float* Wv = (const float*)d_in[5];
  const float* bv = (const float*)d_in[6];
  const float* Wo = (const float*)d_in[7];
  const float* bo = (const float*)d_in[8];
  float* out = (float*)d_out;

  char* w = (char*)d_ws;
  u16* Xb  = (u16*)w; w += (size_t)8192 * 1024 * 2;
  u16* Wqb = (u16*)w; w += (size_t)2048 * 1024 * 2;
  u16* Wkb = (u16*)w; w += (size_t)2048 * 1024 * 2;
  u16* Wvb = (u16*)w; w += (size_t)2048 * 1024 * 2;
  u16* Wob = (u16*)w; w += (size_t)1024 * 2048 * 2;
  u16* Qb  = (u16*)w; w += (size_t)8192 * 2048 * 2;
  u16* Kb  = (u16*)w; w += (size_t)8192 * 2048 * 2;
  u16* Vt  = (u16*)w; w += (size_t)8192 * 2048 * 2;   // fp16 [4][2048 d][2048 t]
  u16* AO  = (u16*)w; w += (size_t)8192 * 2048 * 2;
  u16* Scb = (u16*)w; w += (size_t)8192 * 2048 * 2;   // fp16 scores
  u16* Pb  = (u16*)w; w += (size_t)8192 * 2048 * 2;   // fp16 P
  if ((size_t)(w - (char*)d_ws) > ws_size) return;

  cvt_all<<<16384, 256, 0, stream>>>(X, Wq, Wk, Wv, Wo, Xb, Wqb, Wkb, Wvb, Wob);

  // projections: M=8192, N=2048, K=1024
  gemmK<1, true, 2, 0><<<dim3(8, 32, 1), 512, 0, stream>>>(Xb, Wqb, Qb, bq,
      1024, 1024, 1024, 2048, 0, 0, 0, 1.0f);
  gemmK<1, true, 2, 0><<<dim3(8, 32, 1), 512, 0, stream>>>(Xb, Wkb, Kb, bk,
      1024, 1024, 1024, 2048, 0, 0, 0, 1.0f);
  gemmK<2, true, 2, 0><<<dim3(8, 32, 1), 512, 0, stream>>>(Xb, Wvb, Vt, bv,
      1024, 1024, 1024, 0, 0, 0, 0, 1.0f);

  // scores: per-batch 2048x2048, K=2048, alpha = 1/sqrt(1024) -> fp16 Sc
  gemmK<3, false, 2, 0><<<dim3(8, 8, 4), 512, 0, stream>>>(Qb, Kb, Scb, nullptr,
      2048, 2048, 2048, 2048, 4194304, 4194304, 4194304, 0.03125f);

  softmax_f16<<<8192, 256, 0, stream>>>(Scb, Pb);

  // O = P @ Vt^T : fp16 MFMA -> bf16 AO
  gemmK<1, false, 2, 1><<<dim3(8, 8, 4), 512, 0, stream>>>(Pb, Vt, AO, nullptr,
      2048, 2048, 2048, 2048, 4194304, 4194304, 4194304, 1.0f);

  // out = AO @ Wo^T + bo : M=8192, N=1024, K=2048, fp32 out (256x128 tiles)
  gemmK<0, true, 1, 0><<<dim3(8, 32, 1), 512, 0, stream>>>(AO, Wob, out, bo,
      2048, 2048, 2048, 1024, 0, 0, 0, 1.0f);
}

// Round 20
// 307.913 us; speedup vs baseline: 1.0849x; 1.0849x over previous
//
#include <hip/hip_runtime.h>

// ComplexAttention: B=4, S=2048, D=1024 -> single-head attention, head_dim 2048:
// Q/K/V = X@W^T+b ; S = Q@K^T/32 ; P = softmax(S) ; O = P@V ; out = O@Wo^T + bo.
// R20 = R18 restored verbatim (best verified: 307.4us).  R19's 32x32 MFMA swap
// regressed (6.29M bank conflicts -- the 16x16 layout's conflict-freedom is
// empirical; the 32-row fragment span breaks it).  All axes explored; this is
// the session's verified plateau configuration:
//   - GEMM: 256x(NH*128) tile, BK=64, 8 waves, 1 barrier/K-tile, same-phase
//     reads, hoisted XOR-swizzled addressing, global_load_lds width-16.
//   - fp16 softmax path (Sc/P/V fp16; PV via mfma-f16) halves score traffic.
//   - single fused convert launch; NH=1 256x128 final projection (256 blocks).

typedef short  bf16x8 __attribute__((ext_vector_type(8)));
typedef _Float16 f16x8 __attribute__((ext_vector_type(8)));
typedef float  f32x4  __attribute__((ext_vector_type(4)));
typedef unsigned short u16;

typedef __attribute__((address_space(3))) void       lds_void;
typedef const __attribute__((address_space(1))) void g_void;

__device__ __forceinline__ u16 f2bf(float f) {
  union { float f; unsigned u; } v; v.f = f;
  unsigned r = v.u + 0x7FFFu + ((v.u >> 16) & 1u);   // round-to-nearest-even
  return (u16)(r >> 16);
}
__device__ __forceinline__ u16 f2h(float f) {
  union { _Float16 h; u16 u; } v; v.h = (_Float16)f;
  return v.u;
}
__device__ __forceinline__ float h2f(u16 u) {
  union { u16 u; _Float16 h; } v; v.u = u;
  return (float)v.h;
}

// ------------- fp32 -> bf16 convert, ALL tensors in one launch -------------
// blocks 0..8191: X (2097152 f4); then 4 x 2048 blocks: Wq, Wk, Wv, Wo.
__global__ __launch_bounds__(256) void cvt_all(
    const float* __restrict__ X,  const float* __restrict__ Wq,
    const float* __restrict__ Wk, const float* __restrict__ Wv,
    const float* __restrict__ Wo, u16* __restrict__ Xb, u16* __restrict__ Wqb,
    u16* __restrict__ Wkb, u16* __restrict__ Wvb, u16* __restrict__ Wob) {
  const int bid = blockIdx.x;
  const float* in; u16* out; int lb;
  if (bid < 8192) { in = X; out = Xb; lb = bid; }
  else {
    const int r = bid - 8192, s = r >> 11; lb = r & 2047;
    in  = (s == 0) ? Wq  : (s == 1) ? Wk  : (s == 2) ? Wv  : Wo;
    out = (s == 0) ? Wqb : (s == 1) ? Wkb : (s == 2) ? Wvb : Wob;
  }
  const int i = lb * 256 + threadIdx.x;
  const float4 v = ((const float4*)in)[i];
  union { u16 us[4]; unsigned long long ll; } u;
  u.us[0] = f2bf(v.x); u.us[1] = f2bf(v.y); u.us[2] = f2bf(v.z); u.us[3] = f2bf(v.w);
  ((unsigned long long*)out)[i] = u.ll;
}

// ---------------- 256x(NH*128) NT GEMM, 1 barrier/K-tile, hoisted addressing ----
// C[m,n] = alpha * sum_k A[m,k]*B[n,k] (+ bias[n]).  A,B 16-bit row-major (K contig).
// CMODE: 0=fp32 C, 1=bf16 C, 2=fp16 transposed-V write Vt[b][n][t], 3=fp16 C.
// FT: 0 = bf16 MFMA inputs, 1 = fp16 MFMA inputs (same frag & C/D layout).
// 512 thr = 8 waves (2M x 4N); BK=64; LDS: A [2][256][64]u16 @0, B [2][..][64] @32768.
// LDS u16 layout per (operand,dbuf): half*8192 + q*4096 + w*512 + lane*8 (16B/lane);
// swizzle slot (c^(r&7)) loop-invariant per lane.  Safety (R11/R15, ref-passed):
// per K-tile segment {reads+MMs; stage other buf; own vmcnt(0); BAR}.
template<int CMODE, bool BIAS, int NH, int FT>
__global__ __launch_bounds__(512, 2) void gemmK(const u16* __restrict__ A,
                                                const u16* __restrict__ B,
                                                void* __restrict__ Cv,
                                                const float* __restrict__ bias,
                                                int K, int lda, int ldb, int ldc,
                                                long bsA, long bsB, long bsC,
                                                float alpha)
{
  __shared__ u16 sm[65536];
  const int bz = blockIdx.z;
  const u16* Ab = A + (long)bz * bsA;
  const u16* Bb = B + (long)bz * bsB;
  const int m0 = blockIdx.y * 256, n0 = blockIdx.x * (NH * 128);
  const int tid = threadIdx.x, lane = tid & 63, w = tid >> 6;
  const int wmr = w >> 2, wnr = w & 3;
  const int fr = lane & 15, ko = lane >> 4;

  f32x4 acc[8][2 * NH] = {};
  bf16x8 afA[8], afB[8], bfA[4], bfB[4];

  // ---- hoisted LDS read bases (u16 units; loop-invariant per lane) ----
  const u16* aP0 = sm + wmr * 8192 + fr * 64 + (((0 + ko) ^ (fr & 7)) * 8);  // kk=0
  const u16* aP1 = sm + wmr * 8192 + fr * 64 + (((4 + ko) ^ (fr & 7)) * 8);  // kk=1
  const u16* bP0 = sm + 32768 + wnr * (NH * 32) * 64 + fr * 64 + (((0 + ko) ^ (fr & 7)) * 8);
  const u16* bP1 = sm + 32768 + wnr * (NH * 32) * 64 + fr * 64 + (((4 + ko) ^ (fr & 7)) * 8);

// frag reads: all offsets compile-time (D,MH,NHh literals; mi,ni unrolled)
#define LDAf(dst, D, MH)                                                        \
  { _Pragma("unroll") for (int mi = 0; mi < 4; ++mi) {                          \
      dst[mi * 2 + 0] = *(const bf16x8*)(aP0 + (D) * 16384 + (MH) * 4096 + mi * 1024); \
      dst[mi * 2 + 1] = *(const bf16x8*)(aP1 + (D) * 16384 + (MH) * 4096 + mi * 1024); } }
#define LDBf(dst, D, NHh)                                                       \
  { _Pragma("unroll") for (int ni = 0; ni < 2; ++ni) {                          \
      dst[ni * 2 + 0] = *(const bf16x8*)(bP0 + (D) * 16384 + (NHh) * 2048 + ni * 1024); \
      dst[ni * 2 + 1] = *(const bf16x8*)(bP1 + (D) * 16384 + (NHh) * 2048 + ni * 1024); } }

  // ---- hoisted staging pointers: lane's 16B chunk, row rl = q*64 + w*8 + (lane>>3),
  //      pre-swizzled src col c = ((lane&7) ^ (lane>>3)) * 8  (q/half-invariant) ----
  const int lrow = w * 8 + (lane >> 3);
  const int c8 = ((lane & 7) ^ (lane >> 3)) * 8;
  const long dA = (long)lda * 64, dB = (long)ldb * 64;
  const u16* pA00 = Ab + (long)(m0 + lrow) * lda + c8;       // half0,q0
  const u16* pA01 = pA00 + dA;                               // half0,q1 (+64 rows)
  const u16* pA10 = pA00 + 2 * dA;                           // half1,q0
  const u16* pA11 = pA00 + 3 * dA;                           // half1,q1
  const u16* pB00 = Bb + (long)(n0 + lrow) * ldb + c8;
  const u16* pB01 = pB00 + dB;
  const u16* pB10 = pB00 + 2 * dB;                           // NH==2 only
  const u16* pB11 = pB00 + 3 * dB;
  u16* dstB = sm + w * 512;                                  // + const per call

#define STG(ptr, CONSTOFF)                                                      \
  __builtin_amdgcn_global_load_lds((g_void*)(ptr), (lds_void*)(dstB + (CONSTOFF)), 16, 0, 0);
  // dest const (u16): (isA?0:32768) + D*16384 + HALF*8192 + Q*4096
#define STG_A(D) { STG(pA00, (D)*16384 + 0)        STG(pA01, (D)*16384 + 4096)  \
                   STG(pA10, (D)*16384 + 8192)     STG(pA11, (D)*16384 + 12288) \
                   pA00 += 64; pA01 += 64; pA10 += 64; pA11 += 64; }
#define STG_B2(D) { STG(pB00, 32768 + (D)*16384 + 0)    STG(pB01, 32768 + (D)*16384 + 4096)  \
                    STG(pB10, 32768 + (D)*16384 + 8192) STG(pB11, 32768 + (D)*16384 + 12288) \
                    pB00 += 64; pB01 += 64; pB10 += 64; pB11 += 64; }
#define STG_B1(D) { STG(pB00, 32768 + (D)*16384 + 0)    STG(pB01, 32768 + (D)*16384 + 4096)  \
                    pB00 += 64; pB01 += 64; }

  auto MM = [&](const bf16x8* af, const bf16x8* bf, int mb, int nb) {
    __builtin_amdgcn_s_setprio(1);
#pragma unroll
    for (int mi = 0; mi < 4; ++mi)
#pragma unroll
      for (int ni = 0; ni < 2; ++ni)
#pragma unroll
        for (int kk = 0; kk < 2; ++kk) {
          if constexpr (FT == 0)
            acc[mb + mi][nb + ni] = __builtin_amdgcn_mfma_f32_16x16x32_bf16(
                af[mi * 2 + kk], bf[ni * 2 + kk], acc[mb + mi][nb + ni], 0, 0, 0);
          else
            acc[mb + mi][nb + ni] = __builtin_amdgcn_mfma_f32_16x16x32_f16(
                __builtin_bit_cast(f16x8, af[mi * 2 + kk]),
                __builtin_bit_cast(f16x8, bf[ni * 2 + kk]),
                acc[mb + mi][nb + ni], 0, 0, 0);
        }
    __builtin_amdgcn_s_setprio(0);
  };

// one K-tile on buffer D; stages next tile into buffer D^1 when SEN
#define KTILE2(D, SEN)                                                          \
  { LDAf(afA, D, 0) LDBf(bfA, D, 0)                                             \
    if (SEN) { STG_A(D ^ 1) }                                                   \
    MM(afA, bfA, 0, 0);                                                         \
    LDBf(bfB, D, 1)                                                             \
    if (SEN) { STG_B2(D ^ 1) }                                                  \
    MM(afA, bfB, 0, 2);                                                         \
    LDAf(afB, D, 1)                                                             \
    MM(afB, bfB, 4, 2);                                                         \
    MM(afB, bfA, 4, 0);                                                         \
    asm volatile("s_waitcnt vmcnt(0)" ::: "memory");                            \
    asm volatile("s_barrier" ::: "memory"); }
#define KTILE1(D, SEN)                                                          \
  { LDAf(afA, D, 0) LDBf(bfA, D, 0)                                             \
    if (SEN) { STG_A(D ^ 1) }                                                   \
    MM(afA, bfA, 0, 0);                                                         \
    LDAf(afB, D, 1)                                                             \
    if (SEN) { STG_B1(D ^ 1) }                                                  \
    MM(afB, bfA, 4, 0);                                                         \
    asm volatile("s_waitcnt vmcnt(0)" ::: "memory");                            \
    asm volatile("s_barrier" ::: "memory"); }

  const int nt = K >> 6, niter = nt >> 1;

  // prologue: tile 0 -> buf0; own-drain; barrier.
  STG_A(0)
  if constexpr (NH == 2) { STG_B2(0) } else { STG_B1(0) }
  asm volatile("s_waitcnt vmcnt(0)" ::: "memory");
  asm volatile("s_barrier" ::: "memory");

  for (int j = 0; j < niter; ++j) {
    const bool pre = (j + 1 < niter);
    if constexpr (NH == 2) {
      KTILE2(0, true)          // tile 2j   (buf0), stages 2j+1 -> buf1
      KTILE2(1, pre)           // tile 2j+1 (buf1), stages 2j+2 -> buf0
    } else {
      KTILE1(0, true)
      KTILE1(1, pre)
    }
  }

  // epilogue: C/D frag layout col=lane&15, row=(lane>>4)*4+r  (m89-verified)
  const int col = lane & 15, rb = (lane >> 4) * 4;
#pragma unroll
  for (int mi = 0; mi < 8; ++mi) {
#pragma unroll
    for (int ni = 0; ni < 2 * NH; ++ni) {
      const int mg = m0 + wmr * 128 + mi * 16 + rb;
      const int ng = n0 + wnr * (NH * 32) + ni * 16 + col;
      const float bvv = BIAS ? bias[ng] : 0.0f;
      if constexpr (CMODE == 2) {
        u16* Cc = (u16*)Cv;
        const long bb = mg >> 11;
        const int  t  = mg & 2047;
        union { u16 us[4]; unsigned long long ll; } u;
#pragma unroll
        for (int r = 0; r < 4; ++r) u.us[r] = f2h(acc[mi][ni][r] * alpha + bvv);
        *(unsigned long long*)(Cc + bb * 4194304 + (long)ng * 2048 + t) = u.ll;
      } else if constexpr (CMODE == 1 || CMODE == 3) {
        u16* Cc = (u16*)Cv + (long)bz * bsC;
#pragma unroll
        for (int r = 0; r < 4; ++r) {
          const float x = acc[mi][ni][r] * alpha + bvv;
          Cc[(long)(mg + r) * ldc + ng] = (CMODE == 1) ? f2bf(x) : f2h(x);
        }
      } else {
        float* Cf = (float*)Cv + (long)bz * bsC;
#pragma unroll
        for (int r = 0; r < 4; ++r)
          Cf[(long)(mg + r) * ldc + ng] = acc[mi][ni][r] * alpha + bvv;
      }
    }
  }
#undef LDAf
#undef LDBf
#undef STG
#undef STG_A
#undef STG_B2
#undef STG_B1
#undef KTILE2
#undef KTILE1
}

// ---------------- row softmax: fp16 scores row (2048) -> fp16 P ----------------
__global__ __launch_bounds__(256) void softmax_f16(const u16* __restrict__ Scb,
                                                   u16* __restrict__ Pb) {
  const int tid = threadIdx.x;
  const long row = blockIdx.x;
  union { int4 v; u16 us[8]; } u;
  u.v = ((const int4*)(Scb + row * 2048))[tid];
  float f[8];
#pragma unroll
  for (int j = 0; j < 8; ++j) f[j] = h2f(u.us[j]);
  float mx = f[0];
#pragma unroll
  for (int j = 1; j < 8; ++j) mx = fmaxf(mx, f[j]);
  __shared__ float red[8];
  const int lane = tid & 63, wid = tid >> 6;
#pragma unroll
  for (int off = 32; off; off >>= 1) mx = fmaxf(mx, __shfl_down(mx, off));
  if (!lane) red[wid] = mx;
  __syncthreads();
  mx = fmaxf(fmaxf(red[0], red[1]), fmaxf(red[2], red[3]));
  float e[8], s = 0.f;
#pragma unroll
  for (int j = 0; j < 8; ++j) { e[j] = __expf(f[j] - mx); s += e[j]; }
#pragma unroll
  for (int off = 32; off; off >>= 1) s += __shfl_down(s, off);
  if (!lane) red[4 + wid] = s;
  __syncthreads();
  s = red[4] + red[5] + red[6] + red[7];
  const float inv = 1.0f / s;
  union { u16 us[8]; int4 v; } o;
#pragma unroll
  for (int j = 0; j < 8; ++j) o.us[j] = f2h(e[j] * inv);
  ((int4*)(Pb + row * 2048))[tid] = o.v;
}

extern "C" void kernel_launch(void* const* d_in, const int* in_sizes, int n_in,
                              void* d_out, int out_size, void* d_ws, size_t ws_size,
                              hipStream_t stream) {
  const float* X  = (const float*)d_in[0];
  const float* Wq = (const float*)d_in[1];
  const float* bq = (const float*)d_in[2];
  const float* Wk = (const float*)d_in[3];
  const float* bk = (const float*)d_in[4];
  const float* Wv = (const float*)d_in[5];
  const float* bv = (const float*)d_in[6];
  const float* Wo = (const float*)d_in[7];
  const float* bo = (const float*)d_in[8];
  float* out = (float*)d_out;

  char* w = (char*)d_ws;
  u16* Xb  = (u16*)w; w += (size_t)8192 * 1024 * 2;
  u16* Wqb = (u16*)w; w += (size_t)2048 * 1024 * 2;
  u16* Wkb = (u16*)w; w += (size_t)2048 * 1024 * 2;
  u16* Wvb = (u16*)w; w += (size_t)2048 * 1024 * 2;
  u16* Wob = (u16*)w; w += (size_t)1024 * 2048 * 2;
  u16* Qb  = (u16*)w; w += (size_t)8192 * 2048 * 2;
  u16* Kb  = (u16*)w; w += (size_t)8192 * 2048 * 2;
  u16* Vt  = (u16*)w; w += (size_t)8192 * 2048 * 2;   // fp16 [4][2048 d][2048 t]
  u16* AO  = (u16*)w; w += (size_t)8192 * 2048 * 2;
  u16* Scb = (u16*)w; w += (size_t)8192 * 2048 * 2;   // fp16 scores
  u16* Pb  = (u16*)w; w += (size_t)8192 * 2048 * 2;   // fp16 P
  if ((size_t)(w - (char*)d_ws) > ws_size) return;

  // all 5 converts in one launch (blocks: 8192 X + 4 x 2048 weights)
  cvt_all<<<16384, 256, 0, stream>>>(X, Wq, Wk, Wv, Wo, Xb, Wqb, Wkb, Wvb, Wob);

  // projections: M=8192, N=2048, K=1024 (bf16 in; Q/K out bf16, V out fp16-transposed)
  gemmK<1, true, 2, 0><<<dim3(8, 32, 1), 512, 0, stream>>>(Xb, Wqb, Qb, bq,
      1024, 1024, 1024, 2048, 0, 0, 0, 1.0f);
  gemmK<1, true, 2, 0><<<dim3(8, 32, 1), 512, 0, stream>>>(Xb, Wkb, Kb, bk,
      1024, 1024, 1024, 2048, 0, 0, 0, 1.0f);
  gemmK<2, true, 2, 0><<<dim3(8, 32, 1), 512, 0, stream>>>(Xb, Wvb, Vt, bv,
      1024, 1024, 1024, 0, 0, 0, 0, 1.0f);

  // scores: per-batch 2048x2048, K=2048, alpha = 1/sqrt(1024) -> fp16 Sc
  gemmK<3, false, 2, 0><<<dim3(8, 8, 4), 512, 0, stream>>>(Qb, Kb, Scb, nullptr,
      2048, 2048, 2048, 2048, 4194304, 4194304, 4194304, 0.03125f);

  softmax_f16<<<8192, 256, 0, stream>>>(Scb, Pb);

  // O = P @ Vt^T : fp16 x fp16 MFMA, bf16 AO out
  gemmK<1, false, 2, 1><<<dim3(8, 8, 4), 512, 0, stream>>>(Pb, Vt, AO, nullptr,
      2048, 2048, 2048, 2048, 4194304, 4194304, 4194304, 1.0f);

  // out = AO @ Wo^T + bo : M=8192, N=1024, K=2048, fp32 out (256x128 tiles)
  gemmK<0, true, 1, 0><<<dim3(8, 32, 1), 512, 0, stream>>>(AO, Wob, out, bo,
      2048, 2048, 2048, 1024, 0, 0, 0, 1.0f);
}

// Round 21
// 296.128 us; speedup vs baseline: 1.1281x; 1.0398x over previous
//
#include <hip/hip_runtime.h>

// ComplexAttention: B=4, S=2048, D=1024 -> single-head attention, head_dim 2048:
// Q/K/V = X@W^T+b ; S = Q@K^T/32 ; P = softmax(S) ; O = P@V ; out = O@Wo^T + bo.
// R21 = R20 (verified plateau 307.4/307.9us) + QKV projections fused into ONE
// dispatch: Wqb/Wkb/Wvb are contiguous in ws (a [6144][1024] B matrix) and
// Qb/Kb/Vt are contiguous outputs, so the proven gemmK main loop runs unchanged
// with grid x=24; only the epilogue branches (block-uniform sel = bx>>3):
// sel<2 -> bf16 into Qb/Kb, sel==2 -> fp16 transposed into Vt.  Saves 2 launch
// boundaries + tail overlap between weight panels.

typedef short  bf16x8 __attribute__((ext_vector_type(8)));
typedef _Float16 f16x8 __attribute__((ext_vector_type(8)));
typedef float  f32x4  __attribute__((ext_vector_type(4)));
typedef unsigned short u16;

typedef __attribute__((address_space(3))) void       lds_void;
typedef const __attribute__((address_space(1))) void g_void;

__device__ __forceinline__ u16 f2bf(float f) {
  union { float f; unsigned u; } v; v.f = f;
  unsigned r = v.u + 0x7FFFu + ((v.u >> 16) & 1u);   // round-to-nearest-even
  return (u16)(r >> 16);
}
__device__ __forceinline__ u16 f2h(float f) {
  union { _Float16 h; u16 u; } v; v.h = (_Float16)f;
  return v.u;
}
__device__ __forceinline__ float h2f(u16 u) {
  union { u16 u; _Float16 h; } v; v.u = u;
  return (float)v.h;
}

// ------------- fp32 -> bf16 convert, ALL tensors in one launch -------------
__global__ __launch_bounds__(256) void cvt_all(
    const float* __restrict__ X,  const float* __restrict__ Wq,
    const float* __restrict__ Wk, const float* __restrict__ Wv,
    const float* __restrict__ Wo, u16* __restrict__ Xb, u16* __restrict__ Wqb,
    u16* __restrict__ Wkb, u16* __restrict__ Wvb, u16* __restrict__ Wob) {
  const int bid = blockIdx.x;
  const float* in; u16* out; int lb;
  if (bid < 8192) { in = X; out = Xb; lb = bid; }
  else {
    const int r = bid - 8192, s = r >> 11; lb = r & 2047;
    in  = (s == 0) ? Wq  : (s == 1) ? Wk  : (s == 2) ? Wv  : Wo;
    out = (s == 0) ? Wqb : (s == 1) ? Wkb : (s == 2) ? Wvb : Wob;
  }
  const int i = lb * 256 + threadIdx.x;
  const float4 v = ((const float4*)in)[i];
  union { u16 us[4]; unsigned long long ll; } u;
  u.us[0] = f2bf(v.x); u.us[1] = f2bf(v.y); u.us[2] = f2bf(v.z); u.us[3] = f2bf(v.w);
  ((unsigned long long*)out)[i] = u.ll;
}

// ---------------- 256x(NH*128) NT GEMM, 1 barrier/K-tile, hoisted addressing ----
// C[m,n] = alpha * sum_k A[m,k]*B[n,k] (+ bias[n]).  A,B 16-bit row-major (K contig).
// CMODE: 0=fp32 C, 1=bf16 C, 2=fp16 transposed-V Vt[b][n][t], 3=fp16 C,
//        4=fused QKV: sel=bx>>3 -> {0,1}: bf16 -> Cv + sel*16M (Qb/Kb),
//                                 2: fp16 transposed -> Cv + 32M (Vt).
// FT: 0 = bf16 MFMA inputs, 1 = fp16 MFMA inputs (same frag & C/D layout).
// 512 thr = 8 waves (2M x 4N); BK=64; LDS: A [2][256][64]u16 @0, B [2][..][64] @32768.
// Safety (R11/R15, ref-passed): per K-tile segment {reads+MMs; stage other buf;
// own vmcnt(0); BAR}.
template<int CMODE, bool BIAS, int NH, int FT>
__global__ __launch_bounds__(512, 2) void gemmK(const u16* __restrict__ A,
                                                const u16* __restrict__ B,
                                                void* __restrict__ Cv,
                                                const float* __restrict__ bias,
                                                int K, int lda, int ldb, int ldc,
                                                long bsA, long bsB, long bsC,
                                                float alpha,
                                                const float* __restrict__ bias2,
                                                const float* __restrict__ bias3)
{
  __shared__ u16 sm[65536];
  const int bz = blockIdx.z;
  const u16* Ab = A + (long)bz * bsA;
  const u16* Bb = B + (long)bz * bsB;
  const int m0 = blockIdx.y * 256, n0 = blockIdx.x * (NH * 128);
  const int tid = threadIdx.x, lane = tid & 63, w = tid >> 6;
  const int wmr = w >> 2, wnr = w & 3;
  const int fr = lane & 15, ko = lane >> 4;

  f32x4 acc[8][2 * NH] = {};
  bf16x8 afA[8], afB[8], bfA[4], bfB[4];

  // ---- hoisted LDS read bases (u16 units; loop-invariant per lane) ----
  const u16* aP0 = sm + wmr * 8192 + fr * 64 + (((0 + ko) ^ (fr & 7)) * 8);  // kk=0
  const u16* aP1 = sm + wmr * 8192 + fr * 64 + (((4 + ko) ^ (fr & 7)) * 8);  // kk=1
  const u16* bP0 = sm + 32768 + wnr * (NH * 32) * 64 + fr * 64 + (((0 + ko) ^ (fr & 7)) * 8);
  const u16* bP1 = sm + 32768 + wnr * (NH * 32) * 64 + fr * 64 + (((4 + ko) ^ (fr & 7)) * 8);

// frag reads: all offsets compile-time (D,MH,NHh literals; mi,ni unrolled)
#define LDAf(dst, D, MH)                                                        \
  { _Pragma("unroll") for (int mi = 0; mi < 4; ++mi) {                          \
      dst[mi * 2 + 0] = *(const bf16x8*)(aP0 + (D) * 16384 + (MH) * 4096 + mi * 1024); \
      dst[mi * 2 + 1] = *(const bf16x8*)(aP1 + (D) * 16384 + (MH) * 4096 + mi * 1024); } }
#define LDBf(dst, D, NHh)                                                       \
  { _Pragma("unroll") for (int ni = 0; ni < 2; ++ni) {                          \
      dst[ni * 2 + 0] = *(const bf16x8*)(bP0 + (D) * 16384 + (NHh) * 2048 + ni * 1024); \
      dst[ni * 2 + 1] = *(const bf16x8*)(bP1 + (D) * 16384 + (NHh) * 2048 + ni * 1024); } }

  // ---- hoisted staging pointers: lane's 16B chunk, row rl = q*64 + w*8 + (lane>>3),
  //      pre-swizzled src col c = ((lane&7) ^ (lane>>3)) * 8  (q/half-invariant) ----
  const int lrow = w * 8 + (lane >> 3);
  const int c8 = ((lane & 7) ^ (lane >> 3)) * 8;
  const long dA = (long)lda * 64, dB = (long)ldb * 64;
  const u16* pA00 = Ab + (long)(m0 + lrow) * lda + c8;       // half0,q0
  const u16* pA01 = pA00 + dA;                               // half0,q1 (+64 rows)
  const u16* pA10 = pA00 + 2 * dA;                           // half1,q0
  const u16* pA11 = pA00 + 3 * dA;                           // half1,q1
  const u16* pB00 = Bb + (long)(n0 + lrow) * ldb + c8;
  const u16* pB01 = pB00 + dB;
  const u16* pB10 = pB00 + 2 * dB;                           // NH==2 only
  const u16* pB11 = pB00 + 3 * dB;
  u16* dstB = sm + w * 512;                                  // + const per call

#define STG(ptr, CONSTOFF)                                                      \
  __builtin_amdgcn_global_load_lds((g_void*)(ptr), (lds_void*)(dstB + (CONSTOFF)), 16, 0, 0);
  // dest const (u16): (isA?0:32768) + D*16384 + HALF*8192 + Q*4096
#define STG_A(D) { STG(pA00, (D)*16384 + 0)        STG(pA01, (D)*16384 + 4096)  \
                   STG(pA10, (D)*16384 + 8192)     STG(pA11, (D)*16384 + 12288) \
                   pA00 += 64; pA01 += 64; pA10 += 64; pA11 += 64; }
#define STG_B2(D) { STG(pB00, 32768 + (D)*16384 + 0)    STG(pB01, 32768 + (D)*16384 + 4096)  \
                    STG(pB10, 32768 + (D)*16384 + 8192) STG(pB11, 32768 + (D)*16384 + 12288) \
                    pB00 += 64; pB01 += 64; pB10 += 64; pB11 += 64; }
#define STG_B1(D) { STG(pB00, 32768 + (D)*16384 + 0)    STG(pB01, 32768 + (D)*16384 + 4096)  \
                    pB00 += 64; pB01 += 64; }

  auto MM = [&](const bf16x8* af, const bf16x8* bf, int mb, int nb) {
    __builtin_amdgcn_s_setprio(1);
#pragma unroll
    for (int mi = 0; mi < 4; ++mi)
#pragma unroll
      for (int ni = 0; ni < 2; ++ni)
#pragma unroll
        for (int kk = 0; kk < 2; ++kk) {
          if constexpr (FT == 0)
            acc[mb + mi][nb + ni] = __builtin_amdgcn_mfma_f32_16x16x32_bf16(
                af[mi * 2 + kk], bf[ni * 2 + kk], acc[mb + mi][nb + ni], 0, 0, 0);
          else
            acc[mb + mi][nb + ni] = __builtin_amdgcn_mfma_f32_16x16x32_f16(
                __builtin_bit_cast(f16x8, af[mi * 2 + kk]),
                __builtin_bit_cast(f16x8, bf[ni * 2 + kk]),
                acc[mb + mi][nb + ni], 0, 0, 0);
        }
    __builtin_amdgcn_s_setprio(0);
  };

// one K-tile on buffer D; stages next tile into buffer D^1 when SEN
#define KTILE2(D, SEN)                                                          \
  { LDAf(afA, D, 0) LDBf(bfA, D, 0)                                             \
    if (SEN) { STG_A(D ^ 1) }                                                   \
    MM(afA, bfA, 0, 0);                                                         \
    LDBf(bfB, D, 1)                                                             \
    if (SEN) { STG_B2(D ^ 1) }                                                  \
    MM(afA, bfB, 0, 2);                                                         \
    LDAf(afB, D, 1)                                                             \
    MM(afB, bfB, 4, 2);                                                         \
    MM(afB, bfA, 4, 0);                                                         \
    asm volatile("s_waitcnt vmcnt(0)" ::: "memory");                            \
    asm volatile("s_barrier" ::: "memory"); }
#define KTILE1(D, SEN)                                                          \
  { LDAf(afA, D, 0) LDBf(bfA, D, 0)                                             \
    if (SEN) { STG_A(D ^ 1) }                                                   \
    MM(afA, bfA, 0, 0);                                                         \
    LDAf(afB, D, 1)                                                             \
    if (SEN) { STG_B1(D ^ 1) }                                                  \
    MM(afB, bfA, 4, 0);                                                         \
    asm volatile("s_waitcnt vmcnt(0)" ::: "memory");                            \
    asm volatile("s_barrier" ::: "memory"); }

  const int nt = K >> 6, niter = nt >> 1;

  // prologue: tile 0 -> buf0; own-drain; barrier.
  STG_A(0)
  if constexpr (NH == 2) { STG_B2(0) } else { STG_B1(0) }
  asm volatile("s_waitcnt vmcnt(0)" ::: "memory");
  asm volatile("s_barrier" ::: "memory");

  for (int j = 0; j < niter; ++j) {
    const bool pre = (j + 1 < niter);
    if constexpr (NH == 2) {
      KTILE2(0, true)          // tile 2j   (buf0), stages 2j+1 -> buf1
      KTILE2(1, pre)           // tile 2j+1 (buf1), stages 2j+2 -> buf0
    } else {
      KTILE1(0, true)
      KTILE1(1, pre)
    }
  }

  // epilogue: C/D frag layout col=lane&15, row=(lane>>4)*4+r  (m89-verified)
  const int col = lane & 15, rb = (lane >> 4) * 4;
#pragma unroll
  for (int mi = 0; mi < 8; ++mi) {
#pragma unroll
    for (int ni = 0; ni < 2 * NH; ++ni) {
      const int mg = m0 + wmr * 128 + mi * 16 + rb;
      const int ng = n0 + wnr * (NH * 32) + ni * 16 + col;
      if constexpr (CMODE == 4) {
        // fused QKV: sel block-uniform; ngl = col within the selected weight
        const int sel = (int)(blockIdx.x >> 3);
        const int ngl = ng & 2047;
        const float* bp = (sel == 0) ? bias : (sel == 1) ? bias2 : bias3;
        const float bv4 = bp[ngl];
        if (sel < 2) {
          u16* Cc = (u16*)Cv + (long)sel * 16777216;       // Qb / Kb (contiguous)
#pragma unroll
          for (int r = 0; r < 4; ++r)
            Cc[(long)(mg + r) * 2048 + ngl] = f2bf(acc[mi][ni][r] + bv4);
        } else {
          u16* Vc = (u16*)Cv + 33554432;                   // Vt, fp16 transposed
          const long bb = mg >> 11;
          const int  t  = mg & 2047;
          union { u16 us[4]; unsigned long long ll; } u;
#pragma unroll
          for (int r = 0; r < 4; ++r) u.us[r] = f2h(acc[mi][ni][r] + bv4);
          *(unsigned long long*)(Vc + bb * 4194304 + (long)ngl * 2048 + t) = u.ll;
        }
      } else {
        const float bvv = BIAS ? bias[ng] : 0.0f;
        if constexpr (CMODE == 2) {
          u16* Cc = (u16*)Cv;
          const long bb = mg >> 11;
          const int  t  = mg & 2047;
          union { u16 us[4]; unsigned long long ll; } u;
#pragma unroll
          for (int r = 0; r < 4; ++r) u.us[r] = f2h(acc[mi][ni][r] * alpha + bvv);
          *(unsigned long long*)(Cc + bb * 4194304 + (long)ng * 2048 + t) = u.ll;
        } else if constexpr (CMODE == 1 || CMODE == 3) {
          u16* Cc = (u16*)Cv + (long)bz * bsC;
#pragma unroll
          for (int r = 0; r < 4; ++r) {
            const float x = acc[mi][ni][r] * alpha + bvv;
            Cc[(long)(mg + r) * ldc + ng] = (CMODE == 1) ? f2bf(x) : f2h(x);
          }
        } else if constexpr (CMODE == 0) {
          float* Cf = (float*)Cv + (long)bz * bsC;
#pragma unroll
          for (int r = 0; r < 4; ++r)
            Cf[(long)(mg + r) * ldc + ng] = acc[mi][ni][r] * alpha + bvv;
        }
      }
    }
  }
#undef LDAf
#undef LDBf
#undef STG
#undef STG_A
#undef STG_B2
#undef STG_B1
#undef KTILE2
#undef KTILE1
}

// ---------------- row softmax: fp16 scores row (2048) -> fp16 P ----------------
__global__ __launch_bounds__(256) void softmax_f16(const u16* __restrict__ Scb,
                                                   u16* __restrict__ Pb) {
  const int tid = threadIdx.x;
  const long row = blockIdx.x;
  union { int4 v; u16 us[8]; } u;
  u.v = ((const int4*)(Scb + row * 2048))[tid];
  float f[8];
#pragma unroll
  for (int j = 0; j < 8; ++j) f[j] = h2f(u.us[j]);
  float mx = f[0];
#pragma unroll
  for (int j = 1; j < 8; ++j) mx = fmaxf(mx, f[j]);
  __shared__ float red[8];
  const int lane = tid & 63, wid = tid >> 6;
#pragma unroll
  for (int off = 32; off; off >>= 1) mx = fmaxf(mx, __shfl_down(mx, off));
  if (!lane) red[wid] = mx;
  __syncthreads();
  mx = fmaxf(fmaxf(red[0], red[1]), fmaxf(red[2], red[3]));
  float e[8], s = 0.f;
#pragma unroll
  for (int j = 0; j < 8; ++j) { e[j] = __expf(f[j] - mx); s += e[j]; }
#pragma unroll
  for (int off = 32; off; off >>= 1) s += __shfl_down(s, off);
  if (!lane) red[4 + wid] = s;
  __syncthreads();
  s = red[4] + red[5] + red[6] + red[7];
  const float inv = 1.0f / s;
  union { u16 us[8]; int4 v; } o;
#pragma unroll
  for (int j = 0; j < 8; ++j) o.us[j] = f2h(e[j] * inv);
  ((int4*)(Pb + row * 2048))[tid] = o.v;
}

extern "C" void kernel_launch(void* const* d_in, const int* in_sizes, int n_in,
                              void* d_out, int out_size, void* d_ws, size_t ws_size,
                              hipStream_t stream) {
  const float* X  = (const float*)d_in[0];
  const float* Wq = (const float*)d_in[1];
  const float* bq = (const float*)d_in[2];
  const float* Wk = (const float*)d_in[3];
  const float* bk = (const float*)d_in[4];
  const float* Wv = (const float*)d_in[5];
  const float* bv = (const float*)d_in[6];
  const float* Wo = (const float*)d_in[7];
  const float* bo = (const float*)d_in[8];
  float* out = (float*)d_out;

  char* w = (char*)d_ws;
  u16* Xb  = (u16*)w; w += (size_t)8192 * 1024 * 2;
  u16* Wqb = (u16*)w; w += (size_t)2048 * 1024 * 2;   // Wqb/Wkb/Wvb contiguous:
  u16* Wkb = (u16*)w; w += (size_t)2048 * 1024 * 2;   //   one [6144][1024] matrix
  u16* Wvb = (u16*)w; w += (size_t)2048 * 1024 * 2;
  u16* Wob = (u16*)w; w += (size_t)1024 * 2048 * 2;
  u16* Qb  = (u16*)w; w += (size_t)8192 * 2048 * 2;   // Qb/Kb/Vt contiguous outputs
  u16* Kb  = (u16*)w; w += (size_t)8192 * 2048 * 2;
  u16* Vt  = (u16*)w; w += (size_t)8192 * 2048 * 2;   // fp16 [4][2048 d][2048 t]
  u16* AO  = (u16*)w; w += (size_t)8192 * 2048 * 2;
  u16* Scb = (u16*)w; w += (size_t)8192 * 2048 * 2;   // fp16 scores
  u16* Pb  = (u16*)w; w += (size_t)8192 * 2048 * 2;   // fp16 P
  if ((size_t)(w - (char*)d_ws) > ws_size) return;

  // all 5 converts in one launch (blocks: 8192 X + 4 x 2048 weights)
  cvt_all<<<16384, 256, 0, stream>>>(X, Wq, Wk, Wv, Wo, Xb, Wqb, Wkb, Wvb, Wob);

  // fused QKV projections: M=8192, N=6144 (Wqb|Wkb|Wvb), K=1024 -> Qb|Kb|Vt
  gemmK<4, true, 2, 0><<<dim3(24, 32, 1), 512, 0, stream>>>(Xb, Wqb, Qb, bq,
      1024, 1024, 1024, 2048, 0, 0, 0, 1.0f, bk, bv);

  // scores: per-batch 2048x2048, K=2048, alpha = 1/sqrt(1024) -> fp16 Sc
  gemmK<3, false, 2, 0><<<dim3(8, 8, 4), 512, 0, stream>>>(Qb, Kb, Scb, nullptr,
      2048, 2048, 2048, 2048, 4194304, 4194304, 4194304, 0.03125f, nullptr, nullptr);

  softmax_f16<<<8192, 256, 0, stream>>>(Scb, Pb);

  // O = P @ Vt^T : fp16 x fp16 MFMA, bf16 AO out
  gemmK<1, false, 2, 1><<<dim3(8, 8, 4), 512, 0, stream>>>(Pb, Vt, AO, nullptr,
      2048, 2048, 2048, 2048, 4194304, 4194304, 4194304, 1.0f, nullptr, nullptr);

  // out = AO @ Wo^T + bo : M=8192, N=1024, K=2048, fp32 out (256x128 tiles)
  gemmK<0, true, 1, 0><<<dim3(8, 32, 1), 512, 0, stream>>>(AO, Wob, out, bo,
      2048, 2048, 2048, 1024, 0, 0, 0, 1.0f, nullptr, nullptr);
}

// Round 22
// 267.015 us; speedup vs baseline: 1.2511x; 1.1090x over previous
//
#include <hip/hip_runtime.h>

// ComplexAttention: B=4, S=2048, D=1024 -> single-head attention, head_dim 2048:
// Q/K/V = X@W^T+b ; S = Q@K^T/32 ; P = softmax(S) ; out = P@(V@Wo^T) + bo.
// R22 = R21 (296us) + tail reassociation: (P@V)@Wo^T == P@(V@Wo^T)  (softmax rows
// sum to 1; pure associativity).  Replaces PV (68.7 GF) + final (34.4 GF) with
// VWoT (34.4 GF) + P@VWoT (34.4 GF) -- both NH=1 / 256-block / K=2048 dispatches
// (~33-40us each vs 65.5+33).  V projection now writes natural fp16 (no transpose);
// Wo converted to fp16; AO buffer dropped.  GEMM kernel = proven R15/R16 structure.

typedef short  bf16x8 __attribute__((ext_vector_type(8)));
typedef _Float16 f16x8 __attribute__((ext_vector_type(8)));
typedef float  f32x4  __attribute__((ext_vector_type(4)));
typedef unsigned short u16;

typedef __attribute__((address_space(3))) void       lds_void;
typedef const __attribute__((address_space(1))) void g_void;

__device__ __forceinline__ u16 f2bf(float f) {
  union { float f; unsigned u; } v; v.f = f;
  unsigned r = v.u + 0x7FFFu + ((v.u >> 16) & 1u);   // round-to-nearest-even
  return (u16)(r >> 16);
}
__device__ __forceinline__ u16 f2h(float f) {
  union { _Float16 h; u16 u; } v; v.h = (_Float16)f;
  return v.u;
}
__device__ __forceinline__ float h2f(u16 u) {
  union { u16 u; _Float16 h; } v; v.u = u;
  return (float)v.h;
}

// ------------- fp32 -> 16-bit convert, ALL tensors in one launch -------------
// blocks 0..8191: X; 8192+ : Wq, Wk, Wv (bf16), Wo (fp16 -- used in fp16 VWoT gemm).
__global__ __launch_bounds__(256) void cvt_all(
    const float* __restrict__ X,  const float* __restrict__ Wq,
    const float* __restrict__ Wk, const float* __restrict__ Wv,
    const float* __restrict__ Wo, u16* __restrict__ Xb, u16* __restrict__ Wqb,
    u16* __restrict__ Wkb, u16* __restrict__ Wvb, u16* __restrict__ Wob) {
  const int bid = blockIdx.x;
  const float* in; u16* out; int lb;
  if (bid < 8192) { in = X; out = Xb; lb = bid; }
  else {
    const int r = bid - 8192, s = r >> 11; lb = r & 2047;
    in  = (s == 0) ? Wq  : (s == 1) ? Wk  : (s == 2) ? Wv  : Wo;
    out = (s == 0) ? Wqb : (s == 1) ? Wkb : (s == 2) ? Wvb : Wob;
  }
  const bool toH = (bid >= 14336);           // Wo -> fp16
  const int i = lb * 256 + threadIdx.x;
  const float4 v = ((const float4*)in)[i];
  union { u16 us[4]; unsigned long long ll; } u;
  if (toH) { u.us[0] = f2h(v.x);  u.us[1] = f2h(v.y);  u.us[2] = f2h(v.z);  u.us[3] = f2h(v.w); }
  else     { u.us[0] = f2bf(v.x); u.us[1] = f2bf(v.y); u.us[2] = f2bf(v.z); u.us[3] = f2bf(v.w); }
  ((unsigned long long*)out)[i] = u.ll;
}

// ---------------- 256x(NH*128) NT GEMM, 1 barrier/K-tile, hoisted addressing ----
// C[m,n] = alpha * sum_k A[m,k]*B[n,k] (+ bias[n]).  A,B 16-bit row-major (K contig).
// CMODE: 0=fp32 C, 1=bf16 C, 3=fp16 C,
//        4=fused QKV: sel=bx>>3 -> {0,1}: bf16 -> Cv + sel*16M (Qb/Kb),
//                                 2: fp16 natural -> Cv + 32M (Vb).
// FT: 0 = bf16 MFMA inputs, 1 = fp16 MFMA inputs (same frag & C/D layout).
// 512 thr = 8 waves (2M x 4N); BK=64; LDS: A [2][256][64]u16 @0, B [2][..][64] @32768.
// Safety (R11/R15, ref-passed): per K-tile segment {reads+MMs; stage other buf;
// own vmcnt(0); BAR}.
template<int CMODE, bool BIAS, int NH, int FT>
__global__ __launch_bounds__(512, 2) void gemmK(const u16* __restrict__ A,
                                                const u16* __restrict__ B,
                                                void* __restrict__ Cv,
                                                const float* __restrict__ bias,
                                                int K, int lda, int ldb, int ldc,
                                                long bsA, long bsB, long bsC,
                                                float alpha,
                                                const float* __restrict__ bias2,
                                                const float* __restrict__ bias3)
{
  __shared__ u16 sm[65536];
  const int bz = blockIdx.z;
  const u16* Ab = A + (long)bz * bsA;
  const u16* Bb = B + (long)bz * bsB;
  const int m0 = blockIdx.y * 256, n0 = blockIdx.x * (NH * 128);
  const int tid = threadIdx.x, lane = tid & 63, w = tid >> 6;
  const int wmr = w >> 2, wnr = w & 3;
  const int fr = lane & 15, ko = lane >> 4;

  f32x4 acc[8][2 * NH] = {};
  bf16x8 afA[8], afB[8], bfA[4], bfB[4];

  // ---- hoisted LDS read bases (u16 units; loop-invariant per lane) ----
  const u16* aP0 = sm + wmr * 8192 + fr * 64 + (((0 + ko) ^ (fr & 7)) * 8);  // kk=0
  const u16* aP1 = sm + wmr * 8192 + fr * 64 + (((4 + ko) ^ (fr & 7)) * 8);  // kk=1
  const u16* bP0 = sm + 32768 + wnr * (NH * 32) * 64 + fr * 64 + (((0 + ko) ^ (fr & 7)) * 8);
  const u16* bP1 = sm + 32768 + wnr * (NH * 32) * 64 + fr * 64 + (((4 + ko) ^ (fr & 7)) * 8);

// frag reads: all offsets compile-time (D,MH,NHh literals; mi,ni unrolled)
#define LDAf(dst, D, MH)                                                        \
  { _Pragma("unroll") for (int mi = 0; mi < 4; ++mi) {                          \
      dst[mi * 2 + 0] = *(const bf16x8*)(aP0 + (D) * 16384 + (MH) * 4096 + mi * 1024); \
      dst[mi * 2 + 1] = *(const bf16x8*)(aP1 + (D) * 16384 + (MH) * 4096 + mi * 1024); } }
#define LDBf(dst, D, NHh)                                                       \
  { _Pragma("unroll") for (int ni = 0; ni < 2; ++ni) {                          \
      dst[ni * 2 + 0] = *(const bf16x8*)(bP0 + (D) * 16384 + (NHh) * 2048 + ni * 1024); \
      dst[ni * 2 + 1] = *(const bf16x8*)(bP1 + (D) * 16384 + (NHh) * 2048 + ni * 1024); } }

  // ---- hoisted staging pointers: lane's 16B chunk, row rl = q*64 + w*8 + (lane>>3),
  //      pre-swizzled src col c = ((lane&7) ^ (lane>>3)) * 8  (q/half-invariant) ----
  const int lrow = w * 8 + (lane >> 3);
  const int c8 = ((lane & 7) ^ (lane >> 3)) * 8;
  const long dA = (long)lda * 64, dB = (long)ldb * 64;
  const u16* pA00 = Ab + (long)(m0 + lrow) * lda + c8;       // half0,q0
  const u16* pA01 = pA00 + dA;                               // half0,q1 (+64 rows)
  const u16* pA10 = pA00 + 2 * dA;                           // half1,q0
  const u16* pA11 = pA00 + 3 * dA;                           // half1,q1
  const u16* pB00 = Bb + (long)(n0 + lrow) * ldb + c8;
  const u16* pB01 = pB00 + dB;
  const u16* pB10 = pB00 + 2 * dB;                           // NH==2 only
  const u16* pB11 = pB00 + 3 * dB;
  u16* dstB = sm + w * 512;                                  // + const per call

#define STG(ptr, CONSTOFF)                                                      \
  __builtin_amdgcn_global_load_lds((g_void*)(ptr), (lds_void*)(dstB + (CONSTOFF)), 16, 0, 0);
  // dest const (u16): (isA?0:32768) + D*16384 + HALF*8192 + Q*4096
#define STG_A(D) { STG(pA00, (D)*16384 + 0)        STG(pA01, (D)*16384 + 4096)  \
                   STG(pA10, (D)*16384 + 8192)     STG(pA11, (D)*16384 + 12288) \
                   pA00 += 64; pA01 += 64; pA10 += 64; pA11 += 64; }
#define STG_B2(D) { STG(pB00, 32768 + (D)*16384 + 0)    STG(pB01, 32768 + (D)*16384 + 4096)  \
                    STG(pB10, 32768 + (D)*16384 + 8192) STG(pB11, 32768 + (D)*16384 + 12288) \
                    pB00 += 64; pB01 += 64; pB10 += 64; pB11 += 64; }
#define STG_B1(D) { STG(pB00, 32768 + (D)*16384 + 0)    STG(pB01, 32768 + (D)*16384 + 4096)  \
                    pB00 += 64; pB01 += 64; }

  auto MM = [&](const bf16x8* af, const bf16x8* bf, int mb, int nb) {
    __builtin_amdgcn_s_setprio(1);
#pragma unroll
    for (int mi = 0; mi < 4; ++mi)
#pragma unroll
      for (int ni = 0; ni < 2; ++ni)
#pragma unroll
        for (int kk = 0; kk < 2; ++kk) {
          if constexpr (FT == 0)
            acc[mb + mi][nb + ni] = __builtin_amdgcn_mfma_f32_16x16x32_bf16(
                af[mi * 2 + kk], bf[ni * 2 + kk], acc[mb + mi][nb + ni], 0, 0, 0);
          else
            acc[mb + mi][nb + ni] = __builtin_amdgcn_mfma_f32_16x16x32_f16(
                __builtin_bit_cast(f16x8, af[mi * 2 + kk]),
                __builtin_bit_cast(f16x8, bf[ni * 2 + kk]),
                acc[mb + mi][nb + ni], 0, 0, 0);
        }
    __builtin_amdgcn_s_setprio(0);
  };

// one K-tile on buffer D; stages next tile into buffer D^1 when SEN
#define KTILE2(D, SEN)                                                          \
  { LDAf(afA, D, 0) LDBf(bfA, D, 0)                                             \
    if (SEN) { STG_A(D ^ 1) }                                                   \
    MM(afA, bfA, 0, 0);                                                         \
    LDBf(bfB, D, 1)                                                             \
    if (SEN) { STG_B2(D ^ 1) }                                                  \
    MM(afA, bfB, 0, 2);                                                         \
    LDAf(afB, D, 1)                                                             \
    MM(afB, bfB, 4, 2);                                                         \
    MM(afB, bfA, 4, 0);                                                         \
    asm volatile("s_waitcnt vmcnt(0)" ::: "memory");                            \
    asm volatile("s_barrier" ::: "memory"); }
#define KTILE1(D, SEN)                                                          \
  { LDAf(afA, D, 0) LDBf(bfA, D, 0)                                             \
    if (SEN) { STG_A(D ^ 1) }                                                   \
    MM(afA, bfA, 0, 0);                                                         \
    LDAf(afB, D, 1)                                                             \
    if (SEN) { STG_B1(D ^ 1) }                                                  \
    MM(afB, bfA, 4, 0);                                                         \
    asm volatile("s_waitcnt vmcnt(0)" ::: "memory");                            \
    asm volatile("s_barrier" ::: "memory"); }

  const int nt = K >> 6, niter = nt >> 1;

  // prologue: tile 0 -> buf0; own-drain; barrier.
  STG_A(0)
  if constexpr (NH == 2) { STG_B2(0) } else { STG_B1(0) }
  asm volatile("s_waitcnt vmcnt(0)" ::: "memory");
  asm volatile("s_barrier" ::: "memory");

  for (int j = 0; j < niter; ++j) {
    const bool pre = (j + 1 < niter);
    if constexpr (NH == 2) {
      KTILE2(0, true)          // tile 2j   (buf0), stages 2j+1 -> buf1
      KTILE2(1, pre)           // tile 2j+1 (buf1), stages 2j+2 -> buf0
    } else {
      KTILE1(0, true)
      KTILE1(1, pre)
    }
  }

  // epilogue: C/D frag layout col=lane&15, row=(lane>>4)*4+r  (m89-verified)
  const int col = lane & 15, rb = (lane >> 4) * 4;
#pragma unroll
  for (int mi = 0; mi < 8; ++mi) {
#pragma unroll
    for (int ni = 0; ni < 2 * NH; ++ni) {
      const int mg = m0 + wmr * 128 + mi * 16 + rb;
      const int ng = n0 + wnr * (NH * 32) + ni * 16 + col;
      if constexpr (CMODE == 4) {
        // fused QKV: sel block-uniform; ngl = col within the selected weight
        const int sel = (int)(blockIdx.x >> 3);
        const int ngl = ng & 2047;
        const float* bp = (sel == 0) ? bias : (sel == 1) ? bias2 : bias3;
        const float bv4 = bp[ngl];
        u16* Cc = (u16*)Cv + (long)sel * 16777216;         // Qb / Kb / Vb contiguous
        if (sel < 2) {
#pragma unroll
          for (int r = 0; r < 4; ++r)
            Cc[(long)(mg + r) * 2048 + ngl] = f2bf(acc[mi][ni][r] + bv4);
        } else {
#pragma unroll
          for (int r = 0; r < 4; ++r)
            Cc[(long)(mg + r) * 2048 + ngl] = f2h(acc[mi][ni][r] + bv4);   // V fp16
        }
      } else {
        const float bvv = BIAS ? bias[ng] : 0.0f;
        if constexpr (CMODE == 1 || CMODE == 3) {
          u16* Cc = (u16*)Cv + (long)bz * bsC;
#pragma unroll
          for (int r = 0; r < 4; ++r) {
            const float x = acc[mi][ni][r] * alpha + bvv;
            Cc[(long)(mg + r) * ldc + ng] = (CMODE == 1) ? f2bf(x) : f2h(x);
          }
        } else if constexpr (CMODE == 0) {
          float* Cf = (float*)Cv + (long)bz * bsC;
#pragma unroll
          for (int r = 0; r < 4; ++r)
            Cf[(long)(mg + r) * ldc + ng] = acc[mi][ni][r] * alpha + bvv;
        }
      }
    }
  }
#undef LDAf
#undef LDBf
#undef STG
#undef STG_A
#undef STG_B2
#undef STG_B1
#undef KTILE2
#undef KTILE1
}

// ---------------- row softmax: fp16 scores row (2048) -> fp16 P ----------------
__global__ __launch_bounds__(256) void softmax_f16(const u16* __restrict__ Scb,
                                                   u16* __restrict__ Pb) {
  const int tid = threadIdx.x;
  const long row = blockIdx.x;
  union { int4 v; u16 us[8]; } u;
  u.v = ((const int4*)(Scb + row * 2048))[tid];
  float f[8];
#pragma unroll
  for (int j = 0; j < 8; ++j) f[j] = h2f(u.us[j]);
  float mx = f[0];
#pragma unroll
  for (int j = 1; j < 8; ++j) mx = fmaxf(mx, f[j]);
  __shared__ float red[8];
  const int lane = tid & 63, wid = tid >> 6;
#pragma unroll
  for (int off = 32; off; off >>= 1) mx = fmaxf(mx, __shfl_down(mx, off));
  if (!lane) red[wid] = mx;
  __syncthreads();
  mx = fmaxf(fmaxf(red[0], red[1]), fmaxf(red[2], red[3]));
  float e[8], s = 0.f;
#pragma unroll
  for (int j = 0; j < 8; ++j) { e[j] = __expf(f[j] - mx); s += e[j]; }
#pragma unroll
  for (int off = 32; off; off >>= 1) s += __shfl_down(s, off);
  if (!lane) red[4 + wid] = s;
  __syncthreads();
  s = red[4] + red[5] + red[6] + red[7];
  const float inv = 1.0f / s;
  union { u16 us[8]; int4 v; } o;
#pragma unroll
  for (int j = 0; j < 8; ++j) o.us[j] = f2h(e[j] * inv);
  ((int4*)(Pb + row * 2048))[tid] = o.v;
}

extern "C" void kernel_launch(void* const* d_in, const int* in_sizes, int n_in,
                              void* d_out, int out_size, void* d_ws, size_t ws_size,
                              hipStream_t stream) {
  const float* X  = (const float*)d_in[0];
  const float* Wq = (const float*)d_in[1];
  const float* bq = (const float*)d_in[2];
  const float* Wk = (const float*)d_in[3];
  const float* bk = (const float*)d_in[4];
  const float* Wv = (const float*)d_in[5];
  const float* bv = (const float*)d_in[6];
  const float* Wo = (const float*)d_in[7];
  const float* bo = (const float*)d_in[8];
  float* out = (float*)d_out;

  char* w = (char*)d_ws;
  u16* Xb  = (u16*)w; w += (size_t)8192 * 1024 * 2;
  u16* Wqb = (u16*)w; w += (size_t)2048 * 1024 * 2;   // Wqb/Wkb/Wvb contiguous
  u16* Wkb = (u16*)w; w += (size_t)2048 * 1024 * 2;
  u16* Wvb = (u16*)w; w += (size_t)2048 * 1024 * 2;
  u16* Wob = (u16*)w; w += (size_t)1024 * 2048 * 2;   // fp16
  u16* Qb  = (u16*)w; w += (size_t)8192 * 2048 * 2;   // Qb/Kb/Vb contiguous outputs
  u16* Kb  = (u16*)w; w += (size_t)8192 * 2048 * 2;
  u16* Vb  = (u16*)w; w += (size_t)8192 * 2048 * 2;   // fp16 [4][2048 t][2048 e]
  u16* VWo = (u16*)w; w += (size_t)4096 * 2048 * 2;   // fp16 [4][1024 d][2048 t]
  u16* Scb = (u16*)w; w += (size_t)8192 * 2048 * 2;   // fp16 scores
  u16* Pb  = (u16*)w; w += (size_t)8192 * 2048 * 2;   // fp16 P
  if ((size_t)(w - (char*)d_ws) > ws_size) return;

  // all 5 converts in one launch (Wo -> fp16, rest bf16)
  cvt_all<<<16384, 256, 0, stream>>>(X, Wq, Wk, Wv, Wo, Xb, Wqb, Wkb, Wvb, Wob);

  // fused QKV projections: M=8192, N=6144 (Wqb|Wkb|Wvb), K=1024 -> Qb|Kb|Vb
  gemmK<4, true, 2, 0><<<dim3(24, 32, 1), 512, 0, stream>>>(Xb, Wqb, Qb, bq,
      1024, 1024, 1024, 2048, 0, 0, 0, 1.0f, bk, bv);

  // scores: per-batch 2048x2048, K=2048, alpha = 1/sqrt(1024) -> fp16 Sc
  gemmK<3, false, 2, 0><<<dim3(8, 8, 4), 512, 0, stream>>>(Qb, Kb, Scb, nullptr,
      2048, 2048, 2048, 2048, 4194304, 4194304, 4194304, 0.03125f, nullptr, nullptr);

  softmax_f16<<<8192, 256, 0, stream>>>(Scb, Pb);

  // VWoT[b][d][t] = sum_e Wo[d,e] * V[b][t][e]  (fp16 MFMA; A=Wob shared, B=Vb)
  // M=1024, N=2048 per batch -> NH=1 grid (16,4,4) = 256 blocks
  gemmK<3, false, 1, 1><<<dim3(16, 4, 4), 512, 0, stream>>>(Wob, Vb, VWo, nullptr,
      2048, 2048, 2048, 2048, 0, 4194304, 2097152, 1.0f, nullptr, nullptr);

  // out[b][s][d] = sum_t P[b][s][t] * VWoT[b][d][t] + bo[d]
  // M=2048, N=1024 per batch -> NH=1 grid (8,8,4) = 256 blocks, fp32 out
  gemmK<0, true, 1, 1><<<dim3(8, 8, 4), 512, 0, stream>>>(Pb, VWo, out, bo,
      2048, 2048, 2048, 1024, 4194304, 2097152, 2097152, 1.0f, nullptr, nullptr);
}

// Round 23
// 250.567 us; speedup vs baseline: 1.3332x; 1.0656x over previous
//
#include <hip/hip_runtime.h>

// ComplexAttention: B=4, S=2048, D=1024 -> single-head attention, head_dim 2048.
// R23: Q/K projections ELIMINATED via softmax row-invariance:
//   S = (XWq^T+bq)(XWk^T+bk)^T = X(Wq^T Wk)X^T + [row-const] + X(Wk^T bq)|_t + [const]
// softmax drops row-const terms -> S ~= X*M*X^T + v[t], M = Wq^T Wk (1024^2, tiny),
// v = X*(Wk^T bq).  Score path: 56 GF vs 137.5 GF.  Whole chain fp16 (more precise
// than bf16 QK: logit err ~0.002 vs ~0.02).  Tail stays reassociated (R22):
// out = P@(V@Wo^T)+bo.  GEMMs = proven gemmK (R15 structure).

typedef short  bf16x8 __attribute__((ext_vector_type(8)));
typedef _Float16 f16x8 __attribute__((ext_vector_type(8)));
typedef float  f32x4  __attribute__((ext_vector_type(4)));
typedef unsigned short u16;

typedef __attribute__((address_space(3))) void       lds_void;
typedef const __attribute__((address_space(1))) void g_void;

__device__ __forceinline__ u16 f2bf(float f) {
  union { float f; unsigned u; } v; v.f = f;
  unsigned r = v.u + 0x7FFFu + ((v.u >> 16) & 1u);
  return (u16)(r >> 16);
}
__device__ __forceinline__ u16 f2h(float f) {
  union { _Float16 h; u16 u; } v; v.h = (_Float16)f;
  return v.u;
}
__device__ __forceinline__ float h2f(u16 u) {
  union { u16 u; _Float16 h; } v; v.u = u;
  return (float)v.h;
}

// ------------- fp32 -> fp16 convert: X (8192 blk), Wv (2048), Wo (2048) -------
__global__ __launch_bounds__(256) void cvt_all(
    const float* __restrict__ X, const float* __restrict__ Wv,
    const float* __restrict__ Wo, u16* __restrict__ Xh,
    u16* __restrict__ Wvh, u16* __restrict__ Woh) {
  const int bid = blockIdx.x;
  const float* in; u16* out; int lb;
  if (bid < 8192)       { in = X;  out = Xh;  lb = bid; }
  else if (bid < 10240) { in = Wv; out = Wvh; lb = bid - 8192; }
  else                  { in = Wo; out = Woh; lb = bid - 10240; }
  const int i = lb * 256 + threadIdx.x;
  const float4 v = ((const float4*)in)[i];
  union { u16 us[4]; unsigned long long ll; } u;
  u.us[0] = f2h(v.x); u.us[1] = f2h(v.y); u.us[2] = f2h(v.z); u.us[3] = f2h(v.w);
  ((unsigned long long*)out)[i] = u.ll;
}

// ------------- transpose-convert: W[2048][1024] fp32 -> Wt[1024][2048] fp16 ----
// bid<2048: Wq->Wqt ; else Wk->Wkt.  32x32 LDS tiles, both sides coalesced.
__global__ __launch_bounds__(256) void txp(const float* __restrict__ Wq,
                                           const float* __restrict__ Wk,
                                           u16* __restrict__ Wqt,
                                           u16* __restrict__ Wkt) {
  __shared__ float t[32][33];
  const int bid = blockIdx.x;
  const float* W = (bid < 2048) ? Wq : Wk;
  u16* Wt = (bid < 2048) ? Wqt : Wkt;
  const int r = bid & 2047;
  const int e0 = (r & 63) * 32, d0 = (r >> 6) * 32;
  const int tx = threadIdx.x & 31, ty = threadIdx.x >> 5;
#pragma unroll
  for (int i = 0; i < 4; ++i)
    t[ty + i * 8][tx] = W[(long)(e0 + ty + i * 8) * 1024 + d0 + tx];
  __syncthreads();
#pragma unroll
  for (int i = 0; i < 4; ++i)
    Wt[(long)(d0 + ty + i * 8) * 2048 + e0 + tx] = f2h(t[tx][ty + i * 8]);
}

// ------------- wv[d] = sum_e Wkt[d][e]*bq[e]  (wave per d) -------------------
__global__ __launch_bounds__(256) void wvk(const u16* __restrict__ Wkt,
                                           const float* __restrict__ bq,
                                           float* __restrict__ wv) {
  const int lane = threadIdx.x & 63, wid = threadIdx.x >> 6;
  const int d = blockIdx.x * 4 + wid;
  float s = 0.f;
  for (int i = 0; i < 32; ++i)
    s += h2f(Wkt[(long)d * 2048 + i * 64 + lane]) * bq[i * 64 + lane];
#pragma unroll
  for (int off = 32; off; off >>= 1) s += __shfl_down(s, off);
  if (!lane) wv[d] = s;
}

// ------------- vv[r] = sum_d Xh[r][d]*wv[d]  (wave per row r) ----------------
__global__ __launch_bounds__(256) void vck(const u16* __restrict__ Xh,
                                           const float* __restrict__ wv,
                                           float* __restrict__ vv) {
  const int lane = threadIdx.x & 63, wid = threadIdx.x >> 6;
  const long r = blockIdx.x * 4 + wid;
  float s = 0.f;
#pragma unroll
  for (int j = 0; j < 16; ++j)
    s += h2f(Xh[r * 1024 + lane * 16 + j]) * wv[lane * 16 + j];
#pragma unroll
  for (int off = 32; off; off >>= 1) s += __shfl_down(s, off);
  if (!lane) vv[r] = s;
}

// ------------- reduce 8 fp32 K-chunk partials -> fp16 MT ---------------------
__global__ __launch_bounds__(256) void redMT(const float* __restrict__ P,
                                             u16* __restrict__ MTh) {
  const int i = blockIdx.x * 256 + threadIdx.x;       // float4 index, 262144 total
  float4 s = ((const float4*)P)[i];
#pragma unroll
  for (int z = 1; z < 8; ++z) {
    const float4 p = ((const float4*)P)[z * 262144 + i];
    s.x += p.x; s.y += p.y; s.z += p.z; s.w += p.w;
  }
  union { u16 us[4]; unsigned long long ll; } u;
  u.us[0] = f2h(s.x); u.us[1] = f2h(s.y); u.us[2] = f2h(s.z); u.us[3] = f2h(s.w);
  ((unsigned long long*)MTh)[i] = u.ll;
}

// ---------------- 256x(NH*128) NT GEMM (proven R15 structure) ----------------
// C[m,n] = alpha * sum_k A[m,k]*B[n,k] (+ bias[n]).  A,B fp16/bf16 row-major.
// CMODE: 0=fp32 C, 1=bf16 C, 3=fp16 C.  FT: 0=bf16 MFMA, 1=fp16 MFMA.
// 512 thr = 8 waves (2M x 4N); BK=64; LDS dbuf + XOR swizzle; 1 barrier/K-tile.
template<int CMODE, bool BIAS, int NH, int FT>
__global__ __launch_bounds__(512, 2) void gemmK(const u16* __restrict__ A,
                                                const u16* __restrict__ B,
                                                void* __restrict__ Cv,
                                                const float* __restrict__ bias,
                                                int K, int lda, int ldb, int ldc,
                                                long bsA, long bsB, long bsC,
                                                float alpha)
{
  __shared__ u16 sm[65536];
  const int bz = blockIdx.z;
  const u16* Ab = A + (long)bz * bsA;
  const u16* Bb = B + (long)bz * bsB;
  const int m0 = blockIdx.y * 256, n0 = blockIdx.x * (NH * 128);
  const int tid = threadIdx.x, lane = tid & 63, w = tid >> 6;
  const int wmr = w >> 2, wnr = w & 3;
  const int fr = lane & 15, ko = lane >> 4;

  f32x4 acc[8][2 * NH] = {};
  bf16x8 afA[8], afB[8], bfA[4], bfB[4];

  const u16* aP0 = sm + wmr * 8192 + fr * 64 + (((0 + ko) ^ (fr & 7)) * 8);
  const u16* aP1 = sm + wmr * 8192 + fr * 64 + (((4 + ko) ^ (fr & 7)) * 8);
  const u16* bP0 = sm + 32768 + wnr * (NH * 32) * 64 + fr * 64 + (((0 + ko) ^ (fr & 7)) * 8);
  const u16* bP1 = sm + 32768 + wnr * (NH * 32) * 64 + fr * 64 + (((4 + ko) ^ (fr & 7)) * 8);

#define LDAf(dst, D, MH)                                                        \
  { _Pragma("unroll") for (int mi = 0; mi < 4; ++mi) {                          \
      dst[mi * 2 + 0] = *(const bf16x8*)(aP0 + (D) * 16384 + (MH) * 4096 + mi * 1024); \
      dst[mi * 2 + 1] = *(const bf16x8*)(aP1 + (D) * 16384 + (MH) * 4096 + mi * 1024); } }
#define LDBf(dst, D, NHh)                                                       \
  { _Pragma("unroll") for (int ni = 0; ni < 2; ++ni) {                          \
      dst[ni * 2 + 0] = *(const bf16x8*)(bP0 + (D) * 16384 + (NHh) * 2048 + ni * 1024); \
      dst[ni * 2 + 1] = *(const bf16x8*)(bP1 + (D) * 16384 + (NHh) * 2048 + ni * 1024); } }

  const int lrow = w * 8 + (lane >> 3);
  const int c8 = ((lane & 7) ^ (lane >> 3)) * 8;
  const long dA = (long)lda * 64, dB = (long)ldb * 64;
  const u16* pA00 = Ab + (long)(m0 + lrow) * lda + c8;
  const u16* pA01 = pA00 + dA;
  const u16* pA10 = pA00 + 2 * dA;
  const u16* pA11 = pA00 + 3 * dA;
  const u16* pB00 = Bb + (long)(n0 + lrow) * ldb + c8;
  const u16* pB01 = pB00 + dB;
  const u16* pB10 = pB00 + 2 * dB;                           // NH==2 only
  const u16* pB11 = pB00 + 3 * dB;
  u16* dstB = sm + w * 512;

#define STG(ptr, CONSTOFF)                                                      \
  __builtin_amdgcn_global_load_lds((g_void*)(ptr), (lds_void*)(dstB + (CONSTOFF)), 16, 0, 0);
#define STG_A(D) { STG(pA00, (D)*16384 + 0)        STG(pA01, (D)*16384 + 4096)  \
                   STG(pA10, (D)*16384 + 8192)     STG(pA11, (D)*16384 + 12288) \
                   pA00 += 64; pA01 += 64; pA10 += 64; pA11 += 64; }
#define STG_B2(D) { STG(pB00, 32768 + (D)*16384 + 0)    STG(pB01, 32768 + (D)*16384 + 4096)  \
                    STG(pB10, 32768 + (D)*16384 + 8192) STG(pB11, 32768 + (D)*16384 + 12288) \
                    pB00 += 64; pB01 += 64; pB10 += 64; pB11 += 64; }
#define STG_B1(D) { STG(pB00, 32768 + (D)*16384 + 0)    STG(pB01, 32768 + (D)*16384 + 4096)  \
                    pB00 += 64; pB01 += 64; }

  auto MM = [&](const bf16x8* af, const bf16x8* bf, int mb, int nb) {
    __builtin_amdgcn_s_setprio(1);
#pragma unroll
    for (int mi = 0; mi < 4; ++mi)
#pragma unroll
      for (int ni = 0; ni < 2; ++ni)
#pragma unroll
        for (int kk = 0; kk < 2; ++kk) {
          if constexpr (FT == 0)
            acc[mb + mi][nb + ni] = __builtin_amdgcn_mfma_f32_16x16x32_bf16(
                af[mi * 2 + kk], bf[ni * 2 + kk], acc[mb + mi][nb + ni], 0, 0, 0);
          else
            acc[mb + mi][nb + ni] = __builtin_amdgcn_mfma_f32_16x16x32_f16(
                __builtin_bit_cast(f16x8, af[mi * 2 + kk]),
                __builtin_bit_cast(f16x8, bf[ni * 2 + kk]),
                acc[mb + mi][nb + ni], 0, 0, 0);
        }
    __builtin_amdgcn_s_setprio(0);
  };

#define KTILE2(D, SEN)                                                          \
  { LDAf(afA, D, 0) LDBf(bfA, D, 0)                                             \
    if (SEN) { STG_A(D ^ 1) }                                                   \
    MM(afA, bfA, 0, 0);                                                         \
    LDBf(bfB, D, 1)                                                             \
    if (SEN) { STG_B2(D ^ 1) }                                                  \
    MM(afA, bfB, 0, 2);                                                         \
    LDAf(afB, D, 1)                                                             \
    MM(afB, bfB, 4, 2);                                                         \
    MM(afB, bfA, 4, 0);                                                         \
    asm volatile("s_waitcnt vmcnt(0)" ::: "memory");                            \
    asm volatile("s_barrier" ::: "memory"); }
#define KTILE1(D, SEN)                                                          \
  { LDAf(afA, D, 0) LDBf(bfA, D, 0)                                             \
    if (SEN) { STG_A(D ^ 1) }                                                   \
    MM(afA, bfA, 0, 0);                                                         \
    LDAf(afB, D, 1)                                                             \
    if (SEN) { STG_B1(D ^ 1) }                                                  \
    MM(afB, bfA, 4, 0);                                                         \
    asm volatile("s_waitcnt vmcnt(0)" ::: "memory");                            \
    asm volatile("s_barrier" ::: "memory"); }

  const int nt = K >> 6, niter = nt >> 1;

  STG_A(0)
  if constexpr (NH == 2) { STG_B2(0) } else { STG_B1(0) }
  asm volatile("s_waitcnt vmcnt(0)" ::: "memory");
  asm volatile("s_barrier" ::: "memory");

  for (int j = 0; j < niter; ++j) {
    const bool pre = (j + 1 < niter);
    if constexpr (NH == 2) {
      KTILE2(0, true)
      KTILE2(1, pre)
    } else {
      KTILE1(0, true)
      KTILE1(1, pre)
    }
  }

  // epilogue: C/D frag layout col=lane&15, row=(lane>>4)*4+r  (m89-verified)
  const int col = lane & 15, rb = (lane >> 4) * 4;
#pragma unroll
  for (int mi = 0; mi < 8; ++mi) {
#pragma unroll
    for (int ni = 0; ni < 2 * NH; ++ni) {
      const int mg = m0 + wmr * 128 + mi * 16 + rb;
      const int ng = n0 + wnr * (NH * 32) + ni * 16 + col;
      const float bvv = BIAS ? bias[ng] : 0.0f;
      if constexpr (CMODE == 1 || CMODE == 3) {
        u16* Cc = (u16*)Cv + (long)bz * bsC;
#pragma unroll
        for (int r = 0; r < 4; ++r) {
          const float x = acc[mi][ni][r] * alpha + bvv;
          Cc[(long)(mg + r) * ldc + ng] = (CMODE == 1) ? f2bf(x) : f2h(x);
        }
      } else {
        float* Cf = (float*)Cv + (long)bz * bsC;
#pragma unroll
        for (int r = 0; r < 4; ++r)
          Cf[(long)(mg + r) * ldc + ng] = acc[mi][ni][r] * alpha + bvv;
      }
    }
  }
#undef LDAf
#undef LDBf
#undef STG
#undef STG_A
#undef STG_B2
#undef STG_B1
#undef KTILE2
#undef KTILE1
}

// ------- row softmax: fp16 S row + v-column-term -> fp16 P -------------------
__global__ __launch_bounds__(256) void softmax_v(const u16* __restrict__ Scb,
                                                 const float* __restrict__ vv,
                                                 u16* __restrict__ Pb) {
  const int tid = threadIdx.x;
  const long row = blockIdx.x;
  const long vb = (row >> 11) << 11;       // start of this batch's v (per column t)
  union { int4 v; u16 us[8]; } u;
  u.v = ((const int4*)(Scb + row * 2048))[tid];
  float f[8];
#pragma unroll
  for (int j = 0; j < 8; ++j)
    f[j] = h2f(u.us[j]) + 0.03125f * vv[vb + tid * 8 + j];
  float mx = f[0];
#pragma unroll
  for (int j = 1; j < 8; ++j) mx = fmaxf(mx, f[j]);
  __shared__ float red[8];
  const int lane = tid & 63, wid = tid >> 6;
#pragma unroll
  for (int off = 32; off; off >>= 1) mx = fmaxf(mx, __shfl_down(mx, off));
  if (!lane) red[wid] = mx;
  __syncthreads();
  mx = fmaxf(fmaxf(red[0], red[1]), fmaxf(red[2], red[3]));
  float e[8], s = 0.f;
#pragma unroll
  for (int j = 0; j < 8; ++j) { e[j] = __expf(f[j] - mx); s += e[j]; }
#pragma unroll
  for (int off = 32; off; off >>= 1) s += __shfl_down(s, off);
  if (!lane) red[4 + wid] = s;
  __syncthreads();
  s = red[4] + red[5] + red[6] + red[7];
  const float inv = 1.0f / s;
  union { u16 us[8]; int4 v; } o;
#pragma unroll
  for (int j = 0; j < 8; ++j) o.us[j] = f2h(e[j] * inv);
  ((int4*)(Pb + row * 2048))[tid] = o.v;
}

extern "C" void kernel_launch(void* const* d_in, const int* in_sizes, int n_in,
                              void* d_out, int out_size, void* d_ws, size_t ws_size,
                              hipStream_t stream) {
  const float* X  = (const float*)d_in[0];
  const float* Wq = (const float*)d_in[1];
  const float* bq = (const float*)d_in[2];
  const float* Wk = (const float*)d_in[3];
  const float* Wv = (const float*)d_in[5];
  const float* bv = (const float*)d_in[6];
  const float* Wo = (const float*)d_in[7];
  const float* bo = (const float*)d_in[8];
  float* out = (float*)d_out;

  char* w = (char*)d_ws;
  u16* Xh   = (u16*)w; w += (size_t)8192 * 1024 * 2;    // fp16 X
  u16* Wvh  = (u16*)w; w += (size_t)2048 * 1024 * 2;    // fp16 Wv
  u16* Woh  = (u16*)w; w += (size_t)1024 * 2048 * 2;    // fp16 Wo
  u16* Wqt  = (u16*)w; w += (size_t)1024 * 2048 * 2;    // fp16 Wq^T
  u16* Wkt  = (u16*)w; w += (size_t)1024 * 2048 * 2;    // fp16 Wk^T
  u16* Vb   = (u16*)w; w += (size_t)8192 * 2048 * 2;    // fp16 V [4][2048 t][2048 e]
  u16* VWo  = (u16*)w; w += (size_t)4096 * 2048 * 2;    // fp16 [4][1024 d][2048 t]
  u16* Scb  = (u16*)w; w += (size_t)8192 * 2048 * 2;    // fp16 scores
  u16* Pb   = (u16*)w; w += (size_t)8192 * 2048 * 2;    // fp16 P
  u16* Tb   = (u16*)w; w += (size_t)8192 * 1024 * 2;    // fp16 T = X*M
  u16* MTh  = (u16*)w; w += (size_t)1024 * 1024 * 2;    // fp16 MT[d2][d1]
  float* wv = (float*)w; w += (size_t)1024 * 4;         // Wk^T bq
  float* vv = (float*)w; w += (size_t)8192 * 4;         // X * wv
  float* Mp = (float*)w; w += (size_t)8 * 1024 * 1024 * 4;  // split-K partials
  if ((size_t)(w - (char*)d_ws) > ws_size) return;

  cvt_all<<<12288, 256, 0, stream>>>(X, Wv, Wo, Xh, Wvh, Woh);
  txp<<<4096, 256, 0, stream>>>(Wq, Wk, Wqt, Wkt);
  wvk<<<256, 256, 0, stream>>>(Wkt, bq, wv);
  vck<<<2048, 256, 0, stream>>>(Xh, wv, vv);

  // V = Xh @ Wvh^T + bv  (fp16 out): M=8192, N=2048, K=1024
  gemmK<3, true, 2, 1><<<dim3(8, 32, 1), 512, 0, stream>>>(Xh, Wvh, Vb, bv,
      1024, 1024, 1024, 2048, 0, 0, 0, 1.0f);

  // MT partials: MT[d2,d1] = sum_e Wkt[d2,e]*Wqt[d1,e], split-K 8x256 via bz
  gemmK<0, false, 1, 1><<<dim3(8, 4, 8), 512, 0, stream>>>(Wkt, Wqt, Mp, nullptr,
      256, 2048, 2048, 1024, 256, 256, 1048576, 1.0f);
  redMT<<<1024, 256, 0, stream>>>(Mp, MTh);

  // T = Xh @ MT^T : M=8192, N=1024, K=1024  (fp16 out)
  gemmK<3, false, 1, 1><<<dim3(8, 32, 1), 512, 0, stream>>>(Xh, MTh, Tb, nullptr,
      1024, 1024, 1024, 1024, 0, 0, 0, 1.0f);

  // S = (T @ Xh^T)/32 per batch: M=2048, N=2048, K=1024 (fp16 out)
  gemmK<3, false, 2, 1><<<dim3(8, 8, 4), 512, 0, stream>>>(Tb, Xh, Scb, nullptr,
      1024, 1024, 1024, 2048, 2097152, 2097152, 4194304, 0.03125f);

  softmax_v<<<8192, 256, 0, stream>>>(Scb, vv, Pb);

  // VWoT[b][d][t] = sum_e Woh[d,e]*V[b][t][e] : M=1024, N=2048, K=2048
  gemmK<3, false, 1, 1><<<dim3(16, 4, 4), 512, 0, stream>>>(Woh, Vb, VWo, nullptr,
      2048, 2048, 2048, 2048, 0, 4194304, 2097152, 1.0f);

  // out[b][s][d] = sum_t P[b][s][t]*VWoT[b][d][t] + bo : M=2048, N=1024, K=2048
  gemmK<0, true, 1, 1><<<dim3(8, 8, 4), 512, 0, stream>>>(Pb, VWo, out, bo,
      2048, 2048, 2048, 1024, 4194304, 2097152, 2097152, 1.0f);
}

// Round 24
// 224.575 us; speedup vs baseline: 1.4875x; 1.1157x over previous
//
#include <hip/hip_runtime.h>

// ComplexAttention: B=4, S=2048, D=1024 -> single-head attention, head_dim 2048.
// R24 = R23 (250.6us, absmax 0.0039) + bijective XCD chunk swizzle in gemmK
// (T1; R17-verified).  R23's S/T dispatches run at 2.5 TB/s FETCH=139MB ~= the
// whole dispatch time -> HBM-traffic-limited, exactly T1's regime.  Swizzle puts
// all blocks sharing one bx (same B-panel) on one XCD -> panel L2-resident.
// Math (R23): S ~= X(Wq^T Wk)X^T + v[t] (softmax row-invariance kills the other
// terms); out = P@(V@Wo^T)+bo (associativity).  All fp16.

typedef short  bf16x8 __attribute__((ext_vector_type(8)));
typedef _Float16 f16x8 __attribute__((ext_vector_type(8)));
typedef float  f32x4  __attribute__((ext_vector_type(4)));
typedef unsigned short u16;

typedef __attribute__((address_space(3))) void       lds_void;
typedef const __attribute__((address_space(1))) void g_void;

__device__ __forceinline__ u16 f2bf(float f) {
  union { float f; unsigned u; } v; v.f = f;
  unsigned r = v.u + 0x7FFFu + ((v.u >> 16) & 1u);
  return (u16)(r >> 16);
}
__device__ __forceinline__ u16 f2h(float f) {
  union { _Float16 h; u16 u; } v; v.h = (_Float16)f;
  return v.u;
}
__device__ __forceinline__ float h2f(u16 u) {
  union { u16 u; _Float16 h; } v; v.u = u;
  return (float)v.h;
}

// ------------- fp32 -> fp16 convert: X (8192 blk), Wv (2048), Wo (2048) -------
__global__ __launch_bounds__(256) void cvt_all(
    const float* __restrict__ X, const float* __restrict__ Wv,
    const float* __restrict__ Wo, u16* __restrict__ Xh,
    u16* __restrict__ Wvh, u16* __restrict__ Woh) {
  const int bid = blockIdx.x;
  const float* in; u16* out; int lb;
  if (bid < 8192)       { in = X;  out = Xh;  lb = bid; }
  else if (bid < 10240) { in = Wv; out = Wvh; lb = bid - 8192; }
  else                  { in = Wo; out = Woh; lb = bid - 10240; }
  const int i = lb * 256 + threadIdx.x;
  const float4 v = ((const float4*)in)[i];
  union { u16 us[4]; unsigned long long ll; } u;
  u.us[0] = f2h(v.x); u.us[1] = f2h(v.y); u.us[2] = f2h(v.z); u.us[3] = f2h(v.w);
  ((unsigned long long*)out)[i] = u.ll;
}

// ------------- transpose-convert: W[2048][1024] fp32 -> Wt[1024][2048] fp16 ----
__global__ __launch_bounds__(256) void txp(const float* __restrict__ Wq,
                                           const float* __restrict__ Wk,
                                           u16* __restrict__ Wqt,
                                           u16* __restrict__ Wkt) {
  __shared__ float t[32][33];
  const int bid = blockIdx.x;
  const float* W = (bid < 2048) ? Wq : Wk;
  u16* Wt = (bid < 2048) ? Wqt : Wkt;
  const int r = bid & 2047;
  const int e0 = (r & 63) * 32, d0 = (r >> 6) * 32;
  const int tx = threadIdx.x & 31, ty = threadIdx.x >> 5;
#pragma unroll
  for (int i = 0; i < 4; ++i)
    t[ty + i * 8][tx] = W[(long)(e0 + ty + i * 8) * 1024 + d0 + tx];
  __syncthreads();
#pragma unroll
  for (int i = 0; i < 4; ++i)
    Wt[(long)(d0 + ty + i * 8) * 2048 + e0 + tx] = f2h(t[tx][ty + i * 8]);
}

// ------------- wv[d] = sum_e Wkt[d][e]*bq[e]  (wave per d) -------------------
__global__ __launch_bounds__(256) void wvk(const u16* __restrict__ Wkt,
                                           const float* __restrict__ bq,
                                           float* __restrict__ wv) {
  const int lane = threadIdx.x & 63, wid = threadIdx.x >> 6;
  const int d = blockIdx.x * 4 + wid;
  float s = 0.f;
  for (int i = 0; i < 32; ++i)
    s += h2f(Wkt[(long)d * 2048 + i * 64 + lane]) * bq[i * 64 + lane];
#pragma unroll
  for (int off = 32; off; off >>= 1) s += __shfl_down(s, off);
  if (!lane) wv[d] = s;
}

// ------------- vv[r] = sum_d Xh[r][d]*wv[d]  (wave per row r) ----------------
__global__ __launch_bounds__(256) void vck(const u16* __restrict__ Xh,
                                           const float* __restrict__ wv,
                                           float* __restrict__ vv) {
  const int lane = threadIdx.x & 63, wid = threadIdx.x >> 6;
  const long r = blockIdx.x * 4 + wid;
  float s = 0.f;
#pragma unroll
  for (int j = 0; j < 16; ++j)
    s += h2f(Xh[r * 1024 + lane * 16 + j]) * wv[lane * 16 + j];
#pragma unroll
  for (int off = 32; off; off >>= 1) s += __shfl_down(s, off);
  if (!lane) vv[r] = s;
}

// ------------- reduce 8 fp32 K-chunk partials -> fp16 MT ---------------------
__global__ __launch_bounds__(256) void redMT(const float* __restrict__ P,
                                             u16* __restrict__ MTh) {
  const int i = blockIdx.x * 256 + threadIdx.x;       // float4 index, 262144 total
  float4 s = ((const float4*)P)[i];
#pragma unroll
  for (int z = 1; z < 8; ++z) {
    const float4 p = ((const float4*)P)[z * 262144 + i];
    s.x += p.x; s.y += p.y; s.z += p.z; s.w += p.w;
  }
  union { u16 us[4]; unsigned long long ll; } u;
  u.us[0] = f2h(s.x); u.us[1] = f2h(s.y); u.us[2] = f2h(s.z); u.us[3] = f2h(s.w);
  ((unsigned long long*)MTh)[i] = u.ll;
}

// ---------------- 256x(NH*128) NT GEMM (proven R15 structure) + T1 swizzle ----
// C[m,n] = alpha * sum_k A[m,k]*B[n,k] (+ bias[n]).  A,B fp16/bf16 row-major.
// CMODE: 0=fp32 C, 1=bf16 C, 3=fp16 C.  FT: 0=bf16 MFMA, 1=fp16 MFMA.
// 512 thr = 8 waves (2M x 4N); BK=64; LDS dbuf + XOR swizzle; 1 barrier/K-tile.
// XCD chunk swizzle (bijective, nb%8==0; R17-verified): same-xcd blocks share bx
// -> B-panel L2-resident per XCD.
template<int CMODE, bool BIAS, int NH, int FT>
__global__ __launch_bounds__(512, 2) void gemmK(const u16* __restrict__ A,
                                                const u16* __restrict__ B,
                                                void* __restrict__ Cv,
                                                const float* __restrict__ bias,
                                                int K, int lda, int ldb, int ldc,
                                                long bsA, long bsB, long bsC,
                                                float alpha)
{
  __shared__ u16 sm[65536];
  const int gx = gridDim.x, gy = gridDim.y;
  const int nb = gx * gy * gridDim.z;
  const int bid0 = blockIdx.x + gx * (blockIdx.y + gy * blockIdx.z);
  const int nsw = (bid0 & 7) * (nb >> 3) + (bid0 >> 3);
  const int bx = nsw % gx, by = (nsw / gx) % gy, bz = nsw / (gx * gy);

  const u16* Ab = A + (long)bz * bsA;
  const u16* Bb = B + (long)bz * bsB;
  const int m0 = by * 256, n0 = bx * (NH * 128);
  const int tid = threadIdx.x, lane = tid & 63, w = tid >> 6;
  const int wmr = w >> 2, wnr = w & 3;
  const int fr = lane & 15, ko = lane >> 4;

  f32x4 acc[8][2 * NH] = {};
  bf16x8 afA[8], afB[8], bfA[4], bfB[4];

  const u16* aP0 = sm + wmr * 8192 + fr * 64 + (((0 + ko) ^ (fr & 7)) * 8);
  const u16* aP1 = sm + wmr * 8192 + fr * 64 + (((4 + ko) ^ (fr & 7)) * 8);
  const u16* bP0 = sm + 32768 + wnr * (NH * 32) * 64 + fr * 64 + (((0 + ko) ^ (fr & 7)) * 8);
  const u16* bP1 = sm + 32768 + wnr * (NH * 32) * 64 + fr * 64 + (((4 + ko) ^ (fr & 7)) * 8);

#define LDAf(dst, D, MH)                                                        \
  { _Pragma("unroll") for (int mi = 0; mi < 4; ++mi) {                          \
      dst[mi * 2 + 0] = *(const bf16x8*)(aP0 + (D) * 16384 + (MH) * 4096 + mi * 1024); \
      dst[mi * 2 + 1] = *(const bf16x8*)(aP1 + (D) * 16384 + (MH) * 4096 + mi * 1024); } }
#define LDBf(dst, D, NHh)                                                       \
  { _Pragma("unroll") for (int ni = 0; ni < 2; ++ni) {                          \
      dst[ni * 2 + 0] = *(const bf16x8*)(bP0 + (D) * 16384 + (NHh) * 2048 + ni * 1024); \
      dst[ni * 2 + 1] = *(const bf16x8*)(bP1 + (D) * 16384 + (NHh) * 2048 + ni * 1024); } }

  const int lrow = w * 8 + (lane >> 3);
  const int c8 = ((lane & 7) ^ (lane >> 3)) * 8;
  const long dA = (long)lda * 64, dB = (long)ldb * 64;
  const u16* pA00 = Ab + (long)(m0 + lrow) * lda + c8;
  const u16* pA01 = pA00 + dA;
  const u16* pA10 = pA00 + 2 * dA;
  const u16* pA11 = pA00 + 3 * dA;
  const u16* pB00 = Bb + (long)(n0 + lrow) * ldb + c8;
  const u16* pB01 = pB00 + dB;
  const u16* pB10 = pB00 + 2 * dB;                           // NH==2 only
  const u16* pB11 = pB00 + 3 * dB;
  u16* dstB = sm + w * 512;

#define STG(ptr, CONSTOFF)                                                      \
  __builtin_amdgcn_global_load_lds((g_void*)(ptr), (lds_void*)(dstB + (CONSTOFF)), 16, 0, 0);
#define STG_A(D) { STG(pA00, (D)*16384 + 0)        STG(pA01, (D)*16384 + 4096)  \
                   STG(pA10, (D)*16384 + 8192)     STG(pA11, (D)*16384 + 12288) \
                   pA00 += 64; pA01 += 64; pA10 += 64; pA11 += 64; }
#define STG_B2(D) { STG(pB00, 32768 + (D)*16384 + 0)    STG(pB01, 32768 + (D)*16384 + 4096)  \
                    STG(pB10, 32768 + (D)*16384 + 8192) STG(pB11, 32768 + (D)*16384 + 12288) \
                    pB00 += 64; pB01 += 64; pB10 += 64; pB11 += 64; }
#define STG_B1(D) { STG(pB00, 32768 + (D)*16384 + 0)    STG(pB01, 32768 + (D)*16384 + 4096)  \
                    pB00 += 64; pB01 += 64; }

  auto MM = [&](const bf16x8* af, const bf16x8* bf, int mb, int nb2) {
    __builtin_amdgcn_s_setprio(1);
#pragma unroll
    for (int mi = 0; mi < 4; ++mi)
#pragma unroll
      for (int ni = 0; ni < 2; ++ni)
#pragma unroll
        for (int kk = 0; kk < 2; ++kk) {
          if constexpr (FT == 0)
            acc[mb + mi][nb2 + ni] = __builtin_amdgcn_mfma_f32_16x16x32_bf16(
                af[mi * 2 + kk], bf[ni * 2 + kk], acc[mb + mi][nb2 + ni], 0, 0, 0);
          else
            acc[mb + mi][nb2 + ni] = __builtin_amdgcn_mfma_f32_16x16x32_f16(
                __builtin_bit_cast(f16x8, af[mi * 2 + kk]),
                __builtin_bit_cast(f16x8, bf[ni * 2 + kk]),
                acc[mb + mi][nb2 + ni], 0, 0, 0);
        }
    __builtin_amdgcn_s_setprio(0);
  };

#define KTILE2(D, SEN)                                                          \
  { LDAf(afA, D, 0) LDBf(bfA, D, 0)                                             \
    if (SEN) { STG_A(D ^ 1) }                                                   \
    MM(afA, bfA, 0, 0);                                                         \
    LDBf(bfB, D, 1)                                                             \
    if (SEN) { STG_B2(D ^ 1) }                                                  \
    MM(afA, bfB, 0, 2);                                                         \
    LDAf(afB, D, 1)                                                             \
    MM(afB, bfB, 4, 2);                                                         \
    MM(afB, bfA, 4, 0);                                                         \
    asm volatile("s_waitcnt vmcnt(0)" ::: "memory");                            \
    asm volatile("s_barrier" ::: "memory"); }
#define KTILE1(D, SEN)                                                          \
  { LDAf(afA, D, 0) LDBf(bfA, D, 0)                                             \
    if (SEN) { STG_A(D ^ 1) }                                                   \
    MM(afA, bfA, 0, 0);                                                         \
    LDAf(afB, D, 1)                                                             \
    if (SEN) { STG_B1(D ^ 1) }                                                  \
    MM(afB, bfA, 4, 0);                                                         \
    asm volatile("s_waitcnt vmcnt(0)" ::: "memory");                            \
    asm volatile("s_barrier" ::: "memory"); }

  const int nt = K >> 6, niter = nt >> 1;

  STG_A(0)
  if constexpr (NH == 2) { STG_B2(0) } else { STG_B1(0) }
  asm volatile("s_waitcnt vmcnt(0)" ::: "memory");
  asm volatile("s_barrier" ::: "memory");

  for (int j = 0; j < niter; ++j) {
    const bool pre = (j + 1 < niter);
    if constexpr (NH == 2) {
      KTILE2(0, true)
      KTILE2(1, pre)
    } else {
      KTILE1(0, true)
      KTILE1(1, pre)
    }
  }

  // epilogue: C/D frag layout col=lane&15, row=(lane>>4)*4+r  (m89-verified)
  const int col = lane & 15, rb = (lane >> 4) * 4;
#pragma unroll
  for (int mi = 0; mi < 8; ++mi) {
#pragma unroll
    for (int ni = 0; ni < 2 * NH; ++ni) {
      const int mg = m0 + wmr * 128 + mi * 16 + rb;
      const int ng = n0 + wnr * (NH * 32) + ni * 16 + col;
      const float bvv = BIAS ? bias[ng] : 0.0f;
      if constexpr (CMODE == 1 || CMODE == 3) {
        u16* Cc = (u16*)Cv + (long)bz * bsC;
#pragma unroll
        for (int r = 0; r < 4; ++r) {
          const float x = acc[mi][ni][r] * alpha + bvv;
          Cc[(long)(mg + r) * ldc + ng] = (CMODE == 1) ? f2bf(x) : f2h(x);
        }
      } else {
        float* Cf = (float*)Cv + (long)bz * bsC;
#pragma unroll
        for (int r = 0; r < 4; ++r)
          Cf[(long)(mg + r) * ldc + ng] = acc[mi][ni][r] * alpha + bvv;
      }
    }
  }
#undef LDAf
#undef LDBf
#undef STG
#undef STG_A
#undef STG_B2
#undef STG_B1
#undef KTILE2
#undef KTILE1
}

// ------- row softmax: fp16 S row + v-column-term -> fp16 P -------------------
__global__ __launch_bounds__(256) void softmax_v(const u16* __restrict__ Scb,
                                                 const float* __restrict__ vv,
                                                 u16* __restrict__ Pb) {
  const int tid = threadIdx.x;
  const long row = blockIdx.x;
  const long vb = (row >> 11) << 11;
  union { int4 v; u16 us[8]; } u;
  u.v = ((const int4*)(Scb + row * 2048))[tid];
  float f[8];
#pragma unroll
  for (int j = 0; j < 8; ++j)
    f[j] = h2f(u.us[j]) + 0.03125f * vv[vb + tid * 8 + j];
  float mx = f[0];
#pragma unroll
  for (int j = 1; j < 8; ++j) mx = fmaxf(mx, f[j]);
  __shared__ float red[8];
  const int lane = tid & 63, wid = tid >> 6;
#pragma unroll
  for (int off = 32; off; off >>= 1) mx = fmaxf(mx, __shfl_down(mx, off));
  if (!lane) red[wid] = mx;
  __syncthreads();
  mx = fmaxf(fmaxf(red[0], red[1]), fmaxf(red[2], red[3]));
  float e[8], s = 0.f;
#pragma unroll
  for (int j = 0; j < 8; ++j) { e[j] = __expf(f[j] - mx); s += e[j]; }
#pragma unroll
  for (int off = 32; off; off >>= 1) s += __shfl_down(s, off);
  if (!lane) red[4 + wid] = s;
  __syncthreads();
  s = red[4] + red[5] + red[6] + red[7];
  const float inv = 1.0f / s;
  union { u16 us[8]; int4 v; } o;
#pragma unroll
  for (int j = 0; j < 8; ++j) o.us[j] = f2h(e[j] * inv);
  ((int4*)(Pb + row * 2048))[tid] = o.v;
}

extern "C" void kernel_launch(void* const* d_in, const int* in_sizes, int n_in,
                              void* d_out, int out_size, void* d_ws, size_t ws_size,
                              hipStream_t stream) {
  const float* X  = (const float*)d_in[0];
  const float* Wq = (const float*)d_in[1];
  const float* bq = (const float*)d_in[2];
  const float* Wk = (const float*)d_in[3];
  const float* Wv = (const float*)d_in[5];
  const float* bv = (const float*)d_in[6];
  const float* Wo = (const float*)d_in[7];
  const float* bo = (const float*)d_in[8];
  float* out = (float*)d_out;

  char* w = (char*)d_ws;
  u16* Xh   = (u16*)w; w += (size_t)8192 * 1024 * 2;
  u16* Wvh  = (u16*)w; w += (size_t)2048 * 1024 * 2;
  u16* Woh  = (u16*)w; w += (size_t)1024 * 2048 * 2;
  u16* Wqt  = (u16*)w; w += (size_t)1024 * 2048 * 2;
  u16* Wkt  = (u16*)w; w += (size_t)1024 * 2048 * 2;
  u16* Vb   = (u16*)w; w += (size_t)8192 * 2048 * 2;
  u16* VWo  = (u16*)w; w += (size_t)4096 * 2048 * 2;
  u16* Scb  = (u16*)w; w += (size_t)8192 * 2048 * 2;
  u16* Pb   = (u16*)w; w += (size_t)8192 * 2048 * 2;
  u16* Tb   = (u16*)w; w += (size_t)8192 * 1024 * 2;
  u16* MTh  = (u16*)w; w += (size_t)1024 * 1024 * 2;
  float* wv = (float*)w; w += (size_t)1024 * 4;
  float* vv = (float*)w; w += (size_t)8192 * 4;
  float* Mp = (float*)w; w += (size_t)8 * 1024 * 1024 * 4;
  if ((size_t)(w - (char*)d_ws) > ws_size) return;

  cvt_all<<<12288, 256, 0, stream>>>(X, Wv, Wo, Xh, Wvh, Woh);
  txp<<<4096, 256, 0, stream>>>(Wq, Wk, Wqt, Wkt);
  wvk<<<256, 256, 0, stream>>>(Wkt, bq, wv);
  vck<<<2048, 256, 0, stream>>>(Xh, wv, vv);

  // V = Xh @ Wvh^T + bv  (fp16 out): M=8192, N=2048, K=1024
  gemmK<3, true, 2, 1><<<dim3(8, 32, 1), 512, 0, stream>>>(Xh, Wvh, Vb, bv,
      1024, 1024, 1024, 2048, 0, 0, 0, 1.0f);

  // MT partials: MT[d2,d1] = sum_e Wkt[d2,e]*Wqt[d1,e], split-K 8x256 via bz
  gemmK<0, false, 1, 1><<<dim3(8, 4, 8), 512, 0, stream>>>(Wkt, Wqt, Mp, nullptr,
      256, 2048, 2048, 1024, 256, 256, 1048576, 1.0f);
  redMT<<<1024, 256, 0, stream>>>(Mp, MTh);

  // T = Xh @ MT^T : M=8192, N=1024, K=1024  (fp16 out)
  gemmK<3, false, 1, 1><<<dim3(8, 32, 1), 512, 0, stream>>>(Xh, MTh, Tb, nullptr,
      1024, 1024, 1024, 1024, 0, 0, 0, 1.0f);

  // S = (T @ Xh^T)/32 per batch: M=2048, N=2048, K=1024 (fp16 out)
  gemmK<3, false, 2, 1><<<dim3(8, 8, 4), 512, 0, stream>>>(Tb, Xh, Scb, nullptr,
      1024, 1024, 1024, 2048, 2097152, 2097152, 4194304, 0.03125f);

  softmax_v<<<8192, 256, 0, stream>>>(Scb, vv, Pb);

  // VWoT[b][d][t] = sum_e Woh[d,e]*V[b][t][e] : M=1024, N=2048, K=2048
  gemmK<3, false, 1, 1><<<dim3(16, 4, 4), 512, 0, stream>>>(Woh, Vb, VWo, nullptr,
      2048, 2048, 2048, 2048, 0, 4194304, 2097152, 1.0f);

  // out[b][s][d] = sum_t P[b][s][t]*VWoT[b][d][t] + bo : M=2048, N=1024, K=2048
  gemmK<0, true, 1, 1><<<dim3(8, 8, 4), 512, 0, stream>>>(Pb, VWo, out, bo,
      2048, 2048, 2048, 1024, 4194304, 2097152, 2097152, 1.0f);
}

// Round 25
// 199.743 us; speedup vs baseline: 1.6725x; 1.1243x over previous
//
#include <hip/hip_runtime.h>

// ComplexAttention: B=4, S=2048, D=1024 -> single-head attention, head_dim 2048.
// R25 = R24 (224.6us) + V-projection ELIMINATED (symmetric to R23's QK trick):
//   VWoT = Wo@V^T = (Wo Wv)@X^T + (Wo bv)[d];  sum_t P = 1 folds the constant
//   into the final bias: out = P@(G X^T)^T + (Wo bv + bo),  G = Wo Wv (1024^2).
// Full pipeline: precompute {MT=Wk^TWq^T-form, G, wv=Wk^T bq, biasF=Wo bv+bo};
// T = X@MT^T; S = T@X^T/32 + v[t]; P = softmax; VWo = G@X^T; out = P@VWo^T+biasF.
// Post-softmax+proj work: 160 -> 112 GF.  gemmK = proven R15 structure + T1 swizzle.

typedef short  bf16x8 __attribute__((ext_vector_type(8)));
typedef _Float16 f16x8 __attribute__((ext_vector_type(8)));
typedef float  f32x4  __attribute__((ext_vector_type(4)));
typedef unsigned short u16;

typedef __attribute__((address_space(3))) void       lds_void;
typedef const __attribute__((address_space(1))) void g_void;

__device__ __forceinline__ u16 f2bf(float f) {
  union { float f; unsigned u; } v; v.f = f;
  unsigned r = v.u + 0x7FFFu + ((v.u >> 16) & 1u);
  return (u16)(r >> 16);
}
__device__ __forceinline__ u16 f2h(float f) {
  union { _Float16 h; u16 u; } v; v.h = (_Float16)f;
  return v.u;
}
__device__ __forceinline__ float h2f(u16 u) {
  union { u16 u; _Float16 h; } v; v.u = u;
  return (float)v.h;
}

// ------------- fp32 -> fp16 convert: X (8192 blk), Wo (2048) ------------------
__global__ __launch_bounds__(256) void cvt_all(
    const float* __restrict__ X, const float* __restrict__ Wo,
    u16* __restrict__ Xh, u16* __restrict__ Woh) {
  const int bid = blockIdx.x;
  const float* in; u16* out; int lb;
  if (bid < 8192) { in = X;  out = Xh;  lb = bid; }
  else            { in = Wo; out = Woh; lb = bid - 8192; }
  const int i = lb * 256 + threadIdx.x;
  const float4 v = ((const float4*)in)[i];
  union { u16 us[4]; unsigned long long ll; } u;
  u.us[0] = f2h(v.x); u.us[1] = f2h(v.y); u.us[2] = f2h(v.z); u.us[3] = f2h(v.w);
  ((unsigned long long*)out)[i] = u.ll;
}

// ------------- transpose-convert: W[2048][1024] fp32 -> Wt[1024][2048] fp16 ----
// sel = bid>>11: 0->Wq, 1->Wk, 2->Wv.
__global__ __launch_bounds__(256) void txp(const float* __restrict__ Wq,
                                           const float* __restrict__ Wk,
                                           const float* __restrict__ Wv,
                                           u16* __restrict__ Wqt,
                                           u16* __restrict__ Wkt,
                                           u16* __restrict__ Wvt) {
  __shared__ float t[32][33];
  const int bid = blockIdx.x, sel = bid >> 11;
  const float* W = (sel == 0) ? Wq : (sel == 1) ? Wk : Wv;
  u16* Wt = (sel == 0) ? Wqt : (sel == 1) ? Wkt : Wvt;
  const int r = bid & 2047;
  const int e0 = (r & 63) * 32, d0 = (r >> 6) * 32;
  const int tx = threadIdx.x & 31, ty = threadIdx.x >> 5;
#pragma unroll
  for (int i = 0; i < 4; ++i)
    t[ty + i * 8][tx] = W[(long)(e0 + ty + i * 8) * 1024 + d0 + tx];
  __syncthreads();
#pragma unroll
  for (int i = 0; i < 4; ++i)
    Wt[(long)(d0 + ty + i * 8) * 2048 + e0 + tx] = f2h(t[tx][ty + i * 8]);
}

// ------------- o[d] = sum_e Wt[d][e]*b[e] (+ add[d])  (wave per d; K=2048) ----
__global__ __launch_bounds__(256) void wvk(const u16* __restrict__ Wt,
                                           const float* __restrict__ b,
                                           float* __restrict__ o,
                                           const float* __restrict__ add) {
  const int lane = threadIdx.x & 63, wid = threadIdx.x >> 6;
  const int d = blockIdx.x * 4 + wid;
  float s = 0.f;
  for (int i = 0; i < 32; ++i)
    s += h2f(Wt[(long)d * 2048 + i * 64 + lane]) * b[i * 64 + lane];
#pragma unroll
  for (int off = 32; off; off >>= 1) s += __shfl_down(s, off);
  if (!lane) o[d] = s + (add ? add[d] : 0.f);
}

// ------------- vv[r] = sum_d Xh[r][d]*wv[d]  (wave per row r) ----------------
__global__ __launch_bounds__(256) void vck(const u16* __restrict__ Xh,
                                           const float* __restrict__ wv,
                                           float* __restrict__ vv) {
  const int lane = threadIdx.x & 63, wid = threadIdx.x >> 6;
  const long r = blockIdx.x * 4 + wid;
  float s = 0.f;
#pragma unroll
  for (int j = 0; j < 16; ++j)
    s += h2f(Xh[r * 1024 + lane * 16 + j]) * wv[lane * 16 + j];
#pragma unroll
  for (int off = 32; off; off >>= 1) s += __shfl_down(s, off);
  if (!lane) vv[r] = s;
}

// ------------- reduce 8 fp32 K-chunk partials -> fp16 (1024^2 matrix) --------
__global__ __launch_bounds__(256) void redMT(const float* __restrict__ P,
                                             u16* __restrict__ Mh) {
  const int i = blockIdx.x * 256 + threadIdx.x;       // float4 index, 262144 total
  float4 s = ((const float4*)P)[i];
#pragma unroll
  for (int z = 1; z < 8; ++z) {
    const float4 p = ((const float4*)P)[z * 262144 + i];
    s.x += p.x; s.y += p.y; s.z += p.z; s.w += p.w;
  }
  union { u16 us[4]; unsigned long long ll; } u;
  u.us[0] = f2h(s.x); u.us[1] = f2h(s.y); u.us[2] = f2h(s.z); u.us[3] = f2h(s.w);
  ((unsigned long long*)Mh)[i] = u.ll;
}

// ---------------- 256x(NH*128) NT GEMM (proven R15 structure) + T1 swizzle ----
template<int CMODE, bool BIAS, int NH, int FT>
__global__ __launch_bounds__(512, 2) void gemmK(const u16* __restrict__ A,
                                                const u16* __restrict__ B,
                                                void* __restrict__ Cv,
                                                const float* __restrict__ bias,
                                                int K, int lda, int ldb, int ldc,
                                                long bsA, long bsB, long bsC,
                                                float alpha)
{
  __shared__ u16 sm[65536];
  const int gx = gridDim.x, gy = gridDim.y;
  const int nb = gx * gy * gridDim.z;
  const int bid0 = blockIdx.x + gx * (blockIdx.y + gy * blockIdx.z);
  const int nsw = (bid0 & 7) * (nb >> 3) + (bid0 >> 3);
  const int bx = nsw % gx, by = (nsw / gx) % gy, bz = nsw / (gx * gy);

  const u16* Ab = A + (long)bz * bsA;
  const u16* Bb = B + (long)bz * bsB;
  const int m0 = by * 256, n0 = bx * (NH * 128);
  const int tid = threadIdx.x, lane = tid & 63, w = tid >> 6;
  const int wmr = w >> 2, wnr = w & 3;
  const int fr = lane & 15, ko = lane >> 4;

  f32x4 acc[8][2 * NH] = {};
  bf16x8 afA[8], afB[8], bfA[4], bfB[4];

  const u16* aP0 = sm + wmr * 8192 + fr * 64 + (((0 + ko) ^ (fr & 7)) * 8);
  const u16* aP1 = sm + wmr * 8192 + fr * 64 + (((4 + ko) ^ (fr & 7)) * 8);
  const u16* bP0 = sm + 32768 + wnr * (NH * 32) * 64 + fr * 64 + (((0 + ko) ^ (fr & 7)) * 8);
  const u16* bP1 = sm + 32768 + wnr * (NH * 32) * 64 + fr * 64 + (((4 + ko) ^ (fr & 7)) * 8);

#define LDAf(dst, D, MH)                                                        \
  { _Pragma("unroll") for (int mi = 0; mi < 4; ++mi) {                          \
      dst[mi * 2 + 0] = *(const bf16x8*)(aP0 + (D) * 16384 + (MH) * 4096 + mi * 1024); \
      dst[mi * 2 + 1] = *(const bf16x8*)(aP1 + (D) * 16384 + (MH) * 4096 + mi * 1024); } }
#define LDBf(dst, D, NHh)                                                       \
  { _Pragma("unroll") for (int ni = 0; ni < 2; ++ni) {                          \
      dst[ni * 2 + 0] = *(const bf16x8*)(bP0 + (D) * 16384 + (NHh) * 2048 + ni * 1024); \
      dst[ni * 2 + 1] = *(const bf16x8*)(bP1 + (D) * 16384 + (NHh) * 2048 + ni * 1024); } }

  const int lrow = w * 8 + (lane >> 3);
  const int c8 = ((lane & 7) ^ (lane >> 3)) * 8;
  const long dA = (long)lda * 64, dB = (long)ldb * 64;
  const u16* pA00 = Ab + (long)(m0 + lrow) * lda + c8;
  const u16* pA01 = pA00 + dA;
  const u16* pA10 = pA00 + 2 * dA;
  const u16* pA11 = pA00 + 3 * dA;
  const u16* pB00 = Bb + (long)(n0 + lrow) * ldb + c8;
  const u16* pB01 = pB00 + dB;
  const u16* pB10 = pB00 + 2 * dB;                           // NH==2 only
  const u16* pB11 = pB00 + 3 * dB;
  u16* dstB = sm + w * 512;

#define STG(ptr, CONSTOFF)                                                      \
  __builtin_amdgcn_global_load_lds((g_void*)(ptr), (lds_void*)(dstB + (CONSTOFF)), 16, 0, 0);
#define STG_A(D) { STG(pA00, (D)*16384 + 0)        STG(pA01, (D)*16384 + 4096)  \
                   STG(pA10, (D)*16384 + 8192)     STG(pA11, (D)*16384 + 12288) \
                   pA00 += 64; pA01 += 64; pA10 += 64; pA11 += 64; }
#define STG_B2(D) { STG(pB00, 32768 + (D)*16384 + 0)    STG(pB01, 32768 + (D)*16384 + 4096)  \
                    STG(pB10, 32768 + (D)*16384 + 8192) STG(pB11, 32768 + (D)*16384 + 12288) \
                    pB00 += 64; pB01 += 64; pB10 += 64; pB11 += 64; }
#define STG_B1(D) { STG(pB00, 32768 + (D)*16384 + 0)    STG(pB01, 32768 + (D)*16384 + 4096)  \
                    pB00 += 64; pB01 += 64; }

  auto MM = [&](const bf16x8* af, const bf16x8* bf, int mb, int nb2) {
    __builtin_amdgcn_s_setprio(1);
#pragma unroll
    for (int mi = 0; mi < 4; ++mi)
#pragma unroll
      for (int ni = 0; ni < 2; ++ni)
#pragma unroll
        for (int kk = 0; kk < 2; ++kk) {
          if constexpr (FT == 0)
            acc[mb + mi][nb2 + ni] = __builtin_amdgcn_mfma_f32_16x16x32_bf16(
                af[mi * 2 + kk], bf[ni * 2 + kk], acc[mb + mi][nb2 + ni], 0, 0, 0);
          else
            acc[mb + mi][nb2 + ni] = __builtin_amdgcn_mfma_f32_16x16x32_f16(
                __builtin_bit_cast(f16x8, af[mi * 2 + kk]),
                __builtin_bit_cast(f16x8, bf[ni * 2 + kk]),
                acc[mb + mi][nb2 + ni], 0, 0, 0);
        }
    __builtin_amdgcn_s_setprio(0);
  };

#define KTILE2(D, SEN)                                                          \
  { LDAf(afA, D, 0) LDBf(bfA, D, 0)                                             \
    if (SEN) { STG_A(D ^ 1) }                                                   \
    MM(afA, bfA, 0, 0);                                                         \
    LDBf(bfB, D, 1)                                                             \
    if (SEN) { STG_B2(D ^ 1) }                                                  \
    MM(afA, bfB, 0, 2);                                                         \
    LDAf(afB, D, 1)                                                             \
    MM(afB, bfB, 4, 2);                                                         \
    MM(afB, bfA, 4, 0);                                                         \
    asm volatile("s_waitcnt vmcnt(0)" ::: "memory");                            \
    asm volatile("s_barrier" ::: "memory"); }
#define KTILE1(D, SEN)                                                          \
  { LDAf(afA, D, 0) LDBf(bfA, D, 0)                                             \
    if (SEN) { STG_A(D ^ 1) }                                                   \
    MM(afA, bfA, 0, 0);                                                         \
    LDAf(afB, D, 1)                                                             \
    if (SEN) { STG_B1(D ^ 1) }                                                  \
    MM(afB, bfA, 4, 0);                                                         \
    asm volatile("s_waitcnt vmcnt(0)" ::: "memory");                            \
    asm volatile("s_barrier" ::: "memory"); }

  const int nt = K >> 6, niter = nt >> 1;

  STG_A(0)
  if constexpr (NH == 2) { STG_B2(0) } else { STG_B1(0) }
  asm volatile("s_waitcnt vmcnt(0)" ::: "memory");
  asm volatile("s_barrier" ::: "memory");

  for (int j = 0; j < niter; ++j) {
    const bool pre = (j + 1 < niter);
    if constexpr (NH == 2) {
      KTILE2(0, true)
      KTILE2(1, pre)
    } else {
      KTILE1(0, true)
      KTILE1(1, pre)
    }
  }

  const int col = lane & 15, rb = (lane >> 4) * 4;
#pragma unroll
  for (int mi = 0; mi < 8; ++mi) {
#pragma unroll
    for (int ni = 0; ni < 2 * NH; ++ni) {
      const int mg = m0 + wmr * 128 + mi * 16 + rb;
      const int ng = n0 + wnr * (NH * 32) + ni * 16 + col;
      const float bvv = BIAS ? bias[ng] : 0.0f;
      if constexpr (CMODE == 1 || CMODE == 3) {
        u16* Cc = (u16*)Cv + (long)bz * bsC;
#pragma unroll
        for (int r = 0; r < 4; ++r) {
          const float x = acc[mi][ni][r] * alpha + bvv;
          Cc[(long)(mg + r) * ldc + ng] = (CMODE == 1) ? f2bf(x) : f2h(x);
        }
      } else {
        float* Cf = (float*)Cv + (long)bz * bsC;
#pragma unroll
        for (int r = 0; r < 4; ++r)
          Cf[(long)(mg + r) * ldc + ng] = acc[mi][ni][r] * alpha + bvv;
      }
    }
  }
#undef LDAf
#undef LDBf
#undef STG
#undef STG_A
#undef STG_B2
#undef STG_B1
#undef KTILE2
#undef KTILE1
}

// ------- row softmax: fp16 S row + v-column-term -> fp16 P -------------------
__global__ __launch_bounds__(256) void softmax_v(const u16* __restrict__ Scb,
                                                 const float* __restrict__ vv,
                                                 u16* __restrict__ Pb) {
  const int tid = threadIdx.x;
  const long row = blockIdx.x;
  const long vb = (row >> 11) << 11;
  union { int4 v; u16 us[8]; } u;
  u.v = ((const int4*)(Scb + row * 2048))[tid];
  float f[8];
#pragma unroll
  for (int j = 0; j < 8; ++j)
    f[j] = h2f(u.us[j]) + 0.03125f * vv[vb + tid * 8 + j];
  float mx = f[0];
#pragma unroll
  for (int j = 1; j < 8; ++j) mx = fmaxf(mx, f[j]);
  __shared__ float red[8];
  const int lane = tid & 63, wid = tid >> 6;
#pragma unroll
  for (int off = 32; off; off >>= 1) mx = fmaxf(mx, __shfl_down(mx, off));
  if (!lane) red[wid] = mx;
  __syncthreads();
  mx = fmaxf(fmaxf(red[0], red[1]), fmaxf(red[2], red[3]));
  float e[8], s = 0.f;
#pragma unroll
  for (int j = 0; j < 8; ++j) { e[j] = __expf(f[j] - mx); s += e[j]; }
#pragma unroll
  for (int off = 32; off; off >>= 1) s += __shfl_down(s, off);
  if (!lane) red[4 + wid] = s;
  __syncthreads();
  s = red[4] + red[5] + red[6] + red[7];
  const float inv = 1.0f / s;
  union { u16 us[8]; int4 v; } o;
#pragma unroll
  for (int j = 0; j < 8; ++j) o.us[j] = f2h(e[j] * inv);
  ((int4*)(Pb + row * 2048))[tid] = o.v;
}

extern "C" void kernel_launch(void* const* d_in, const int* in_sizes, int n_in,
                              void* d_out, int out_size, void* d_ws, size_t ws_size,
                              hipStream_t stream) {
  const float* X  = (const float*)d_in[0];
  const float* Wq = (const float*)d_in[1];
  const float* bq = (const float*)d_in[2];
  const float* Wk = (const float*)d_in[3];
  const float* Wv = (const float*)d_in[5];
  const float* bv = (const float*)d_in[6];
  const float* Wo = (const float*)d_in[7];
  const float* bo = (const float*)d_in[8];
  float* out = (float*)d_out;

  char* w = (char*)d_ws;
  u16* Xh    = (u16*)w; w += (size_t)8192 * 1024 * 2;
  u16* Woh   = (u16*)w; w += (size_t)1024 * 2048 * 2;
  u16* Wqt   = (u16*)w; w += (size_t)1024 * 2048 * 2;
  u16* Wkt   = (u16*)w; w += (size_t)1024 * 2048 * 2;
  u16* Wvt   = (u16*)w; w += (size_t)1024 * 2048 * 2;
  u16* Gh    = (u16*)w; w += (size_t)1024 * 1024 * 2;   // fp16 G = Wo@Wv
  u16* MTh   = (u16*)w; w += (size_t)1024 * 1024 * 2;   // fp16 MT[d2][d1]
  u16* Tb    = (u16*)w; w += (size_t)8192 * 1024 * 2;   // fp16 T = X@MT^T
  u16* Scb   = (u16*)w; w += (size_t)8192 * 2048 * 2;   // fp16 scores
  u16* Pb    = (u16*)w; w += (size_t)8192 * 2048 * 2;   // fp16 P
  u16* VWo   = (u16*)w; w += (size_t)4096 * 2048 * 2;   // fp16 [4][1024 d][2048 t]
  float* wv  = (float*)w; w += (size_t)1024 * 4;        // Wk^T bq
  float* vv  = (float*)w; w += (size_t)8192 * 4;        // X * wv
  float* bF  = (float*)w; w += (size_t)1024 * 4;        // Wo bv + bo
  float* Mp  = (float*)w; w += (size_t)8 * 1024 * 1024 * 4;  // MT split-K partials
  float* Gp  = (float*)w; w += (size_t)8 * 1024 * 1024 * 4;  // G  split-K partials
  if ((size_t)(w - (char*)d_ws) > ws_size) return;

  cvt_all<<<10240, 256, 0, stream>>>(X, Wo, Xh, Woh);
  txp<<<6144, 256, 0, stream>>>(Wq, Wk, Wv, Wqt, Wkt, Wvt);
  wvk<<<256, 256, 0, stream>>>(Wkt, bq, wv, nullptr);   // wv = Wk^T bq
  wvk<<<256, 256, 0, stream>>>(Woh, bv, bF, bo);        // bF = Wo bv + bo
  vck<<<2048, 256, 0, stream>>>(Xh, wv, vv);            // vv = X wv

  // MT partials: MT[d2,d1] = sum_e Wkt[d2,e]*Wqt[d1,e], split-K 8x256 via bz
  gemmK<0, false, 1, 1><<<dim3(8, 4, 8), 512, 0, stream>>>(Wkt, Wqt, Mp, nullptr,
      256, 2048, 2048, 1024, 256, 256, 1048576, 1.0f);
  // G partials: G[d,f] = sum_e Woh[d,e]*Wvt[f,e], split-K 8x256 via bz
  gemmK<0, false, 1, 1><<<dim3(8, 4, 8), 512, 0, stream>>>(Woh, Wvt, Gp, nullptr,
      256, 2048, 2048, 1024, 256, 256, 1048576, 1.0f);
  redMT<<<1024, 256, 0, stream>>>(Mp, MTh);
  redMT<<<1024, 256, 0, stream>>>(Gp, Gh);

  // T = Xh @ MT^T : M=8192, N=1024, K=1024  (fp16 out)
  gemmK<3, false, 1, 1><<<dim3(8, 32, 1), 512, 0, stream>>>(Xh, MTh, Tb, nullptr,
      1024, 1024, 1024, 1024, 0, 0, 0, 1.0f);

  // S = (T @ Xh^T)/32 per batch: M=2048, N=2048, K=1024 (fp16 out)
  gemmK<3, false, 2, 1><<<dim3(8, 8, 4), 512, 0, stream>>>(Tb, Xh, Scb, nullptr,
      1024, 1024, 1024, 2048, 2097152, 2097152, 4194304, 0.03125f);

  softmax_v<<<8192, 256, 0, stream>>>(Scb, vv, Pb);

  // VWo[b][d][t] = sum_f G[d,f] * X[b][t][f] : M=1024, N=2048, K=1024
  gemmK<3, false, 1, 1><<<dim3(16, 4, 4), 512, 0, stream>>>(Gh, Xh, VWo, nullptr,
      1024, 1024, 1024, 2048, 0, 2097152, 2097152, 1.0f);

  // out[b][s][d] = sum_t P[b][s][t]*VWo[b][d][t] + bF[d] : M=2048, N=1024, K=2048
  gemmK<0, true, 1, 1><<<dim3(8, 8, 4), 512, 0, stream>>>(Pb, VWo, out, bF,
      2048, 2048, 2048, 1024, 4194304, 2097152, 2097152, 1.0f);
}

// Round 26
// 182.878 us; speedup vs baseline: 1.8267x; 1.0922x over previous
//
#include <hip/hip_runtime.h>

// ComplexAttention: B=4, S=2048, D=1024 -> single-head attention, head_dim 2048.
// R26 = R25 (199.7us) + dispatch consolidation (arithmetic unchanged):
//  (1) T=X@M and VWo=G@X^T merged: VWo reframed as X@G^T with transposed epilogue
//      (old CMODE=2 machinery); B=[MT;G] contiguous, grid (8,32) NH=2, block-
//      uniform sel=n0>=1024 -> Tb normal / VWo transposed write.
//  (2) MT=Wk^T-form and G=Wo@Wv merged into one QUAD dispatch: A=[Wkt;Woh],
//      B=[Wqt;Wvt], m-half selects B-half -> only useful quadrants; one reduce.
//  (3) wvk pair merged.  13 -> 10 launches; one fewer full-machine GEMM round.
// Math (R23/R25): S ~= X(Wq^TWk)X^T + v[t]; out = P@(G X^T)^T + (Wo bv + bo).

typedef short  bf16x8 __attribute__((ext_vector_type(8)));
typedef _Float16 f16x8 __attribute__((ext_vector_type(8)));
typedef float  f32x4  __attribute__((ext_vector_type(4)));
typedef unsigned short u16;

typedef __attribute__((address_space(3))) void       lds_void;
typedef const __attribute__((address_space(1))) void g_void;

__device__ __forceinline__ u16 f2h(float f) {
  union { _Float16 h; u16 u; } v; v.h = (_Float16)f;
  return v.u;
}
__device__ __forceinline__ float h2f(u16 u) {
  union { u16 u; _Float16 h; } v; v.u = u;
  return (float)v.h;
}

// ------------- fp32 -> fp16 convert: X (8192 blk), Wo -> WA half1 (2048) ------
__global__ __launch_bounds__(256) void cvt_all(
    const float* __restrict__ X, const float* __restrict__ Wo,
    u16* __restrict__ Xh, u16* __restrict__ WoDst) {
  const int bid = blockIdx.x;
  const float* in; u16* out; int lb;
  if (bid < 8192) { in = X;  out = Xh;    lb = bid; }
  else            { in = Wo; out = WoDst; lb = bid - 8192; }
  const int i = lb * 256 + threadIdx.x;
  const float4 v = ((const float4*)in)[i];
  union { u16 us[4]; unsigned long long ll; } u;
  u.us[0] = f2h(v.x); u.us[1] = f2h(v.y); u.us[2] = f2h(v.z); u.us[3] = f2h(v.w);
  ((unsigned long long*)out)[i] = u.ll;
}

// ------------- transpose-convert: W[2048][1024] fp32 -> Wt[1024][2048] fp16 ----
// sel = bid>>11: 0->Wq->WB(h0), 1->Wk->WA(h0), 2->Wv->WB(h1).
__global__ __launch_bounds__(256) void txp(const float* __restrict__ Wq,
                                           const float* __restrict__ Wk,
                                           const float* __restrict__ Wv,
                                           u16* __restrict__ WBh0,
                                           u16* __restrict__ WAh0,
                                           u16* __restrict__ WBh1) {
  __shared__ float t[32][33];
  const int bid = blockIdx.x, sel = bid >> 11;
  const float* W = (sel == 0) ? Wq : (sel == 1) ? Wk : Wv;
  u16* Wt = (sel == 0) ? WBh0 : (sel == 1) ? WAh0 : WBh1;
  const int r = bid & 2047;
  const int e0 = (r & 63) * 32, d0 = (r >> 6) * 32;
  const int tx = threadIdx.x & 31, ty = threadIdx.x >> 5;
#pragma unroll
  for (int i = 0; i < 4; ++i)
    t[ty + i * 8][tx] = W[(long)(e0 + ty + i * 8) * 1024 + d0 + tx];
  __syncthreads();
#pragma unroll
  for (int i = 0; i < 4; ++i)
    Wt[(long)(d0 + ty + i * 8) * 2048 + e0 + tx] = f2h(t[tx][ty + i * 8]);
}

// ------- merged GEMV pair: bid<256 -> wv=Wkt.bq ; else bF=Woh.bv+bo  (K=2048) --
__global__ __launch_bounds__(256) void wvk2(const u16* __restrict__ WA,
                                            const float* __restrict__ bq,
                                            const float* __restrict__ bv,
                                            const float* __restrict__ bo,
                                            float* __restrict__ wv,
                                            float* __restrict__ bF) {
  const int lane = threadIdx.x & 63, wid = threadIdx.x >> 6;
  const bool second = (blockIdx.x >= 256);
  const int d = (blockIdx.x & 255) * 4 + wid;
  const u16* Wt = WA + (second ? (size_t)1024 * 2048 : 0);
  const float* b = second ? bv : bq;
  float s = 0.f;
  for (int i = 0; i < 32; ++i)
    s += h2f(Wt[(long)d * 2048 + i * 64 + lane]) * b[i * 64 + lane];
#pragma unroll
  for (int off = 32; off; off >>= 1) s += __shfl_down(s, off);
  if (!lane) { if (second) bF[d] = s + bo[d]; else wv[d] = s; }
}

// ------------- vv[r] = sum_d Xh[r][d]*wv[d]  (wave per row r) ----------------
__global__ __launch_bounds__(256) void vck(const u16* __restrict__ Xh,
                                           const float* __restrict__ wv,
                                           float* __restrict__ vv) {
  const int lane = threadIdx.x & 63, wid = threadIdx.x >> 6;
  const long r = blockIdx.x * 4 + wid;
  float s = 0.f;
#pragma unroll
  for (int j = 0; j < 16; ++j)
    s += h2f(Xh[r * 1024 + lane * 16 + j]) * wv[lane * 16 + j];
#pragma unroll
  for (int off = 32; off; off >>= 1) s += __shfl_down(s, off);
  if (!lane) vv[r] = s;
}

// ------------- reduce 8 fp32 K-chunk partials [2048][1024] -> fp16 MG --------
__global__ __launch_bounds__(256) void redMG(const float* __restrict__ P,
                                             u16* __restrict__ MG) {
  const int i = blockIdx.x * 256 + threadIdx.x;       // f4 index over 524288
  float4 s = ((const float4*)P)[i];
#pragma unroll
  for (int z = 1; z < 8; ++z) {
    const float4 p = ((const float4*)P)[(size_t)z * 524288 + i];
    s.x += p.x; s.y += p.y; s.z += p.z; s.w += p.w;
  }
  union { u16 us[4]; unsigned long long ll; } u;
  u.us[0] = f2h(s.x); u.us[1] = f2h(s.y); u.us[2] = f2h(s.z); u.us[3] = f2h(s.w);
  ((unsigned long long*)MG)[i] = u.ll;
}

// ---------------- 256x(NH*128) NT GEMM (proven R15 structure) + T1 swizzle ----
// CMODE: 0=fp32 C, 3=fp16 C, 5=dual: n<1024 -> fp16 Tb[m*1024+n]; n>=1024 ->
// transposed fp16 VWo (=Cv+8388608): [b=m>>11][d=n-1024][t=m&2047] (8B packed).
// QUAD: B-half selected by m-half (Bb += (by>>2)*1024*ldb).  FT: 1 = fp16 MFMA.
template<int CMODE, bool BIAS, int NH, int FT, bool QUAD>
__global__ __launch_bounds__(512, 2) void gemmK(const u16* __restrict__ A,
                                                const u16* __restrict__ B,
                                                void* __restrict__ Cv,
                                                const float* __restrict__ bias,
                                                int K, int lda, int ldb, int ldc,
                                                long bsA, long bsB, long bsC,
                                                float alpha)
{
  __shared__ u16 sm[65536];
  const int gx = gridDim.x, gy = gridDim.y;
  const int nb = gx * gy * gridDim.z;
  const int bid0 = blockIdx.x + gx * (blockIdx.y + gy * blockIdx.z);
  const int nsw = (bid0 & 7) * (nb >> 3) + (bid0 >> 3);
  const int bx = nsw % gx, by = (nsw / gx) % gy, bz = nsw / (gx * gy);

  const u16* Ab = A + (long)bz * bsA;
  const u16* Bb = B + (long)bz * bsB;
  if constexpr (QUAD) Bb += (long)(by >> 2) * 1024 * ldb;
  const int m0 = by * 256, n0 = bx * (NH * 128);
  const int tid = threadIdx.x, lane = tid & 63, w = tid >> 6;
  const int wmr = w >> 2, wnr = w & 3;
  const int fr = lane & 15, ko = lane >> 4;

  f32x4 acc[8][2 * NH] = {};
  bf16x8 afA[8], afB[8], bfA[4], bfB[4];

  const u16* aP0 = sm + wmr * 8192 + fr * 64 + (((0 + ko) ^ (fr & 7)) * 8);
  const u16* aP1 = sm + wmr * 8192 + fr * 64 + (((4 + ko) ^ (fr & 7)) * 8);
  const u16* bP0 = sm + 32768 + wnr * (NH * 32) * 64 + fr * 64 + (((0 + ko) ^ (fr & 7)) * 8);
  const u16* bP1 = sm + 32768 + wnr * (NH * 32) * 64 + fr * 64 + (((4 + ko) ^ (fr & 7)) * 8);

#define LDAf(dst, D, MH)                                                        \
  { _Pragma("unroll") for (int mi = 0; mi < 4; ++mi) {                          \
      dst[mi * 2 + 0] = *(const bf16x8*)(aP0 + (D) * 16384 + (MH) * 4096 + mi * 1024); \
      dst[mi * 2 + 1] = *(const bf16x8*)(aP1 + (D) * 16384 + (MH) * 4096 + mi * 1024); } }
#define LDBf(dst, D, NHh)                                                       \
  { _Pragma("unroll") for (int ni = 0; ni < 2; ++ni) {                          \
      dst[ni * 2 + 0] = *(const bf16x8*)(bP0 + (D) * 16384 + (NHh) * 2048 + ni * 1024); \
      dst[ni * 2 + 1] = *(const bf16x8*)(bP1 + (D) * 16384 + (NHh) * 2048 + ni * 1024); } }

  const int lrow = w * 8 + (lane >> 3);
  const int c8 = ((lane & 7) ^ (lane >> 3)) * 8;
  const long dA = (long)lda * 64, dB = (long)ldb * 64;
  const u16* pA00 = Ab + (long)(m0 + lrow) * lda + c8;
  const u16* pA01 = pA00 + dA;
  const u16* pA10 = pA00 + 2 * dA;
  const u16* pA11 = pA00 + 3 * dA;
  const u16* pB00 = Bb + (long)(n0 + lrow) * ldb + c8;
  const u16* pB01 = pB00 + dB;
  const u16* pB10 = pB00 + 2 * dB;                           // NH==2 only
  const u16* pB11 = pB00 + 3 * dB;
  u16* dstB = sm + w * 512;

#define STG(ptr, CONSTOFF)                                                      \
  __builtin_amdgcn_global_load_lds((g_void*)(ptr), (lds_void*)(dstB + (CONSTOFF)), 16, 0, 0);
#define STG_A(D) { STG(pA00, (D)*16384 + 0)        STG(pA01, (D)*16384 + 4096)  \
                   STG(pA10, (D)*16384 + 8192)     STG(pA11, (D)*16384 + 12288) \
                   pA00 += 64; pA01 += 64; pA10 += 64; pA11 += 64; }
#define STG_B2(D) { STG(pB00, 32768 + (D)*16384 + 0)    STG(pB01, 32768 + (D)*16384 + 4096)  \
                    STG(pB10, 32768 + (D)*16384 + 8192) STG(pB11, 32768 + (D)*16384 + 12288) \
                    pB00 += 64; pB01 += 64; pB10 += 64; pB11 += 64; }
#define STG_B1(D) { STG(pB00, 32768 + (D)*16384 + 0)    STG(pB01, 32768 + (D)*16384 + 4096)  \
                    pB00 += 64; pB01 += 64; }

  auto MM = [&](const bf16x8* af, const bf16x8* bf, int mb, int nb2) {
    __builtin_amdgcn_s_setprio(1);
#pragma unroll
    for (int mi = 0; mi < 4; ++mi)
#pragma unroll
      for (int ni = 0; ni < 2; ++ni)
#pragma unroll
        for (int kk = 0; kk < 2; ++kk)
          acc[mb + mi][nb2 + ni] = __builtin_amdgcn_mfma_f32_16x16x32_f16(
              __builtin_bit_cast(f16x8, af[mi * 2 + kk]),
              __builtin_bit_cast(f16x8, bf[ni * 2 + kk]),
              acc[mb + mi][nb2 + ni], 0, 0, 0);
    __builtin_amdgcn_s_setprio(0);
  };

#define KTILE2(D, SEN)                                                          \
  { LDAf(afA, D, 0) LDBf(bfA, D, 0)                                             \
    if (SEN) { STG_A(D ^ 1) }                                                   \
    MM(afA, bfA, 0, 0);                                                         \
    LDBf(bfB, D, 1)                                                             \
    if (SEN) { STG_B2(D ^ 1) }                                                  \
    MM(afA, bfB, 0, 2);                                                         \
    LDAf(afB, D, 1)                                                             \
    MM(afB, bfB, 4, 2);                                                         \
    MM(afB, bfA, 4, 0);                                                         \
    asm volatile("s_waitcnt vmcnt(0)" ::: "memory");                            \
    asm volatile("s_barrier" ::: "memory"); }
#define KTILE1(D, SEN)                                                          \
  { LDAf(afA, D, 0) LDBf(bfA, D, 0)                                             \
    if (SEN) { STG_A(D ^ 1) }                                                   \
    MM(afA, bfA, 0, 0);                                                         \
    LDAf(afB, D, 1)                                                             \
    if (SEN) { STG_B1(D ^ 1) }                                                  \
    MM(afB, bfA, 4, 0);                                                         \
    asm volatile("s_waitcnt vmcnt(0)" ::: "memory");                            \
    asm volatile("s_barrier" ::: "memory"); }

  const int nt = K >> 6, niter = nt >> 1;

  STG_A(0)
  if constexpr (NH == 2) { STG_B2(0) } else { STG_B1(0) }
  asm volatile("s_waitcnt vmcnt(0)" ::: "memory");
  asm volatile("s_barrier" ::: "memory");

  for (int j = 0; j < niter; ++j) {
    const bool pre = (j + 1 < niter);
    if constexpr (NH == 2) {
      KTILE2(0, true)
      KTILE2(1, pre)
    } else {
      KTILE1(0, true)
      KTILE1(1, pre)
    }
  }

  // epilogue: C/D frag layout col=lane&15, row=(lane>>4)*4+r  (m89-verified)
  const int col = lane & 15, rb = (lane >> 4) * 4;
#pragma unroll
  for (int mi = 0; mi < 8; ++mi) {
#pragma unroll
    for (int ni = 0; ni < 2 * NH; ++ni) {
      const int mg = m0 + wmr * 128 + mi * 16 + rb;
      const int ng = n0 + wnr * (NH * 32) + ni * 16 + col;
      if constexpr (CMODE == 5) {
        if (n0 < 1024) {                                   // T half: fp16 normal
          u16* Cc = (u16*)Cv;
#pragma unroll
          for (int r = 0; r < 4; ++r)
            Cc[(long)(mg + r) * 1024 + ng] = f2h(acc[mi][ni][r]);
        } else {                                           // VWo half: transposed
          u16* Vc = (u16*)Cv + 8388608;
          const long bb = mg >> 11;
          const int  t  = mg & 2047, d = ng - 1024;
          union { u16 us[4]; unsigned long long ll; } u;
#pragma unroll
          for (int r = 0; r < 4; ++r) u.us[r] = f2h(acc[mi][ni][r]);
          *(unsigned long long*)(Vc + bb * 2097152 + (long)d * 2048 + t) = u.ll;
        }
      } else {
        const float bvv = BIAS ? bias[ng] : 0.0f;
        if constexpr (CMODE == 3) {
          u16* Cc = (u16*)Cv + (long)bz * bsC;
#pragma unroll
          for (int r = 0; r < 4; ++r)
            Cc[(long)(mg + r) * ldc + ng] = f2h(acc[mi][ni][r] * alpha + bvv);
        } else {
          float* Cf = (float*)Cv + (long)bz * bsC;
#pragma unroll
          for (int r = 0; r < 4; ++r)
            Cf[(long)(mg + r) * ldc + ng] = acc[mi][ni][r] * alpha + bvv;
        }
      }
    }
  }
#undef LDAf
#undef LDBf
#undef STG
#undef STG_A
#undef STG_B2
#undef STG_B1
#undef KTILE2
#undef KTILE1
}

// ------- row softmax: fp16 S row + v-column-term -> fp16 P -------------------
__global__ __launch_bounds__(256) void softmax_v(const u16* __restrict__ Scb,
                                                 const float* __restrict__ vv,
                                                 u16* __restrict__ Pb) {
  const int tid = threadIdx.x;
  const long row = blockIdx.x;
  const long vb = (row >> 11) << 11;
  union { int4 v; u16 us[8]; } u;
  u.v = ((const int4*)(Scb + row * 2048))[tid];
  float f[8];
#pragma unroll
  for (int j = 0; j < 8; ++j)
    f[j] = h2f(u.us[j]) + 0.03125f * vv[vb + tid * 8 + j];
  float mx = f[0];
#pragma unroll
  for (int j = 1; j < 8; ++j) mx = fmaxf(mx, f[j]);
  __shared__ float red[8];
  const int lane = tid & 63, wid = tid >> 6;
#pragma unroll
  for (int off = 32; off; off >>= 1) mx = fmaxf(mx, __shfl_down(mx, off));
  if (!lane) red[wid] = mx;
  __syncthreads();
  mx = fmaxf(fmaxf(red[0], red[1]), fmaxf(red[2], red[3]));
  float e[8], s = 0.f;
#pragma unroll
  for (int j = 0; j < 8; ++j) { e[j] = __expf(f[j] - mx); s += e[j]; }
#pragma unroll
  for (int off = 32; off; off >>= 1) s += __shfl_down(s, off);
  if (!lane) red[4 + wid] = s;
  __syncthreads();
  s = red[4] + red[5] + red[6] + red[7];
  const float inv = 1.0f / s;
  union { u16 us[8]; int4 v; } o;
#pragma unroll
  for (int j = 0; j < 8; ++j) o.us[j] = f2h(e[j] * inv);
  ((int4*)(Pb + row * 2048))[tid] = o.v;
}

extern "C" void kernel_launch(void* const* d_in, const int* in_sizes, int n_in,
                              void* d_out, int out_size, void* d_ws, size_t ws_size,
                              hipStream_t stream) {
  const float* X  = (const float*)d_in[0];
  const float* Wq = (const float*)d_in[1];
  const float* bq = (const float*)d_in[2];
  const float* Wk = (const float*)d_in[3];
  const float* Wv = (const float*)d_in[5];
  const float* bv = (const float*)d_in[6];
  const float* Wo = (const float*)d_in[7];
  const float* bo = (const float*)d_in[8];
  float* out = (float*)d_out;

  char* w = (char*)d_ws;
  u16* Xh   = (u16*)w; w += (size_t)8192 * 1024 * 2;
  u16* WA   = (u16*)w; w += (size_t)2048 * 2048 * 2;   // [Wkt ; Woh]
  u16* WB   = (u16*)w; w += (size_t)2048 * 2048 * 2;   // [Wqt ; Wvt]
  u16* MG   = (u16*)w; w += (size_t)2048 * 1024 * 2;   // [MT ; G] fp16
  u16* Tb   = (u16*)w; w += (size_t)8192 * 1024 * 2;   // fp16 T (VWo follows)
  u16* VWo  = (u16*)w; w += (size_t)4096 * 2048 * 2;   // fp16 [4][1024 d][2048 t]
  u16* Scb  = (u16*)w; w += (size_t)8192 * 2048 * 2;   // fp16 scores
  u16* Pb   = (u16*)w; w += (size_t)8192 * 2048 * 2;   // fp16 P
  float* wv = (float*)w; w += (size_t)1024 * 4;        // Wk^T bq
  float* vv = (float*)w; w += (size_t)8192 * 4;        // X wv
  float* bF = (float*)w; w += (size_t)1024 * 4;        // Wo bv + bo
  float* Pp = (float*)w; w += (size_t)8 * 2048 * 1024 * 4;  // QUAD partials
  if ((size_t)(w - (char*)d_ws) > ws_size) return;
  (void)VWo;

  cvt_all<<<10240, 256, 0, stream>>>(X, Wo, Xh, WA + (size_t)1024 * 2048);
  txp<<<6144, 256, 0, stream>>>(Wq, Wk, Wv, WB, WA, WB + (size_t)1024 * 2048);
  wvk2<<<512, 256, 0, stream>>>(WA, bq, bv, bo, wv, bF);
  vck<<<2048, 256, 0, stream>>>(Xh, wv, vv);

  // QUAD weight products: C[m<1024]=MT partial, C[m>=1024]=G partial; K=2048 via 8x256
  gemmK<0, false, 2, 1, true><<<dim3(4, 8, 8), 512, 0, stream>>>(WA, WB, Pp, nullptr,
      256, 2048, 2048, 1024, 256, 256, 2097152, 1.0f);
  redMG<<<2048, 256, 0, stream>>>(Pp, MG);

  // merged T | VWo: A=Xh, B=[MT;G], M=8192, N=2048, K=1024
  gemmK<5, false, 2, 1, false><<<dim3(8, 32, 1), 512, 0, stream>>>(Xh, MG, Tb, nullptr,
      1024, 1024, 1024, 1024, 0, 0, 0, 1.0f);

  // S = (T @ Xh^T)/32 per batch: M=2048, N=2048, K=1024 (fp16 out)
  gemmK<3, false, 2, 1, false><<<dim3(8, 8, 4), 512, 0, stream>>>(Tb, Xh, Scb, nullptr,
      1024, 1024, 1024, 2048, 2097152, 2097152, 4194304, 0.03125f);

  softmax_v<<<8192, 256, 0, stream>>>(Scb, vv, Pb);

  // out[b][s][d] = sum_t P[b][s][t]*VWo[b][d][t] + bF[d] : M=2048, N=1024, K=2048
  gemmK<0, true, 1, 1, false><<<dim3(8, 8, 4), 512, 0, stream>>>(Pb, Tb + 8388608, out, bF,
      2048, 2048, 2048, 1024, 4194304, 2097152, 2097152, 1.0f);
}

// Round 27
// 170.863 us; speedup vs baseline: 1.9551x; 1.0703x over previous
//
#include <hip/hip_runtime.h>

// ComplexAttention: B=4, S=2048, D=1024 -> single-head attention, head_dim 2048.
// R27 = R26 (182.9us) + preprocessing trims: (a) QUAD split-K partials stored
// fp16 (error ~7e-4 << absmax 0.0039; reuses CMODE=3 bz-strided epilogue) ->
// redMG traffic halves; (b) cvt_all+txp merged into one launch.
// Math (R23/R25): S ~= X(Wq^TWk)X^T + v[t] (softmax row-invariance);
// out = P@(G X^T)^T + (Wo bv + bo) (associativity + row-sum=1).  All fp16.

typedef short  bf16x8 __attribute__((ext_vector_type(8)));
typedef _Float16 f16x8 __attribute__((ext_vector_type(8)));
typedef float  f32x4  __attribute__((ext_vector_type(4)));
typedef unsigned short u16;

typedef __attribute__((address_space(3))) void       lds_void;
typedef const __attribute__((address_space(1))) void g_void;

__device__ __forceinline__ u16 f2h(float f) {
  union { _Float16 h; u16 u; } v; v.h = (_Float16)f;
  return v.u;
}
__device__ __forceinline__ float h2f(u16 u) {
  union { u16 u; _Float16 h; } v; v.u = u;
  return (float)v.h;
}

// ------- merged convert + transpose-convert, one launch -----------------------
// bid<8192: X->Xh (f4); <10240: Wo->WA half1; <16384: transpose Wq/Wk/Wv.
__global__ __launch_bounds__(256) void cvt_txp(
    const float* __restrict__ X,  const float* __restrict__ Wo,
    const float* __restrict__ Wq, const float* __restrict__ Wk,
    const float* __restrict__ Wv, u16* __restrict__ Xh,
    u16* __restrict__ WA, u16* __restrict__ WB) {
  __shared__ float t[32][33];
  const int bid = blockIdx.x;
  if (bid < 10240) {
    const float* in = (bid < 8192) ? X : Wo;
    u16* out = (bid < 8192) ? Xh : (WA + (size_t)1024 * 2048);
    const int lb = (bid < 8192) ? bid : bid - 8192;
    const int i = lb * 256 + threadIdx.x;
    const float4 v = ((const float4*)in)[i];
    union { u16 us[4]; unsigned long long ll; } u;
    u.us[0] = f2h(v.x); u.us[1] = f2h(v.y); u.us[2] = f2h(v.z); u.us[3] = f2h(v.w);
    ((unsigned long long*)out)[i] = u.ll;
    return;
  }
  const int r0 = bid - 10240, sel = r0 >> 11;         // 0:Wq 1:Wk 2:Wv
  const float* W = (sel == 0) ? Wq : (sel == 1) ? Wk : Wv;
  u16* Wt = (sel == 0) ? WB : (sel == 1) ? WA : (WB + (size_t)1024 * 2048);
  const int r = r0 & 2047;
  const int e0 = (r & 63) * 32, d0 = (r >> 6) * 32;
  const int tx = threadIdx.x & 31, ty = threadIdx.x >> 5;
#pragma unroll
  for (int i = 0; i < 4; ++i)
    t[ty + i * 8][tx] = W[(long)(e0 + ty + i * 8) * 1024 + d0 + tx];
  __syncthreads();
#pragma unroll
  for (int i = 0; i < 4; ++i)
    Wt[(long)(d0 + ty + i * 8) * 2048 + e0 + tx] = f2h(t[tx][ty + i * 8]);
}

// ------- merged GEMV pair: bid<256 -> wv=Wkt.bq ; else bF=Woh.bv+bo  (K=2048) --
__global__ __launch_bounds__(256) void wvk2(const u16* __restrict__ WA,
                                            const float* __restrict__ bq,
                                            const float* __restrict__ bv,
                                            const float* __restrict__ bo,
                                            float* __restrict__ wv,
                                            float* __restrict__ bF) {
  const int lane = threadIdx.x & 63, wid = threadIdx.x >> 6;
  const bool second = (blockIdx.x >= 256);
  const int d = (blockIdx.x & 255) * 4 + wid;
  const u16* Wt = WA + (second ? (size_t)1024 * 2048 : 0);
  const float* b = second ? bv : bq;
  float s = 0.f;
  for (int i = 0; i < 32; ++i)
    s += h2f(Wt[(long)d * 2048 + i * 64 + lane]) * b[i * 64 + lane];
#pragma unroll
  for (int off = 32; off; off >>= 1) s += __shfl_down(s, off);
  if (!lane) { if (second) bF[d] = s + bo[d]; else wv[d] = s; }
}

// ------------- vv[r] = sum_d Xh[r][d]*wv[d]  (wave per row r) ----------------
__global__ __launch_bounds__(256) void vck(const u16* __restrict__ Xh,
                                           const float* __restrict__ wv,
                                           float* __restrict__ vv) {
  const int lane = threadIdx.x & 63, wid = threadIdx.x >> 6;
  const long r = blockIdx.x * 4 + wid;
  float s = 0.f;
#pragma unroll
  for (int j = 0; j < 16; ++j)
    s += h2f(Xh[r * 1024 + lane * 16 + j]) * wv[lane * 16 + j];
#pragma unroll
  for (int off = 32; off; off >>= 1) s += __shfl_down(s, off);
  if (!lane) vv[r] = s;
}

// ------------- reduce 8 fp16 K-chunk partials [2048][1024] -> fp16 MG --------
__global__ __launch_bounds__(256) void redMG(const u16* __restrict__ P,
                                             u16* __restrict__ MG) {
  const int i = blockIdx.x * 256 + threadIdx.x;       // u64 index over 524288
  float s0 = 0.f, s1 = 0.f, s2 = 0.f, s3 = 0.f;
#pragma unroll
  for (int z = 0; z < 8; ++z) {
    union { unsigned long long ll; u16 us[4]; } p;
    p.ll = ((const unsigned long long*)P)[(size_t)z * 524288 + i];
    s0 += h2f(p.us[0]); s1 += h2f(p.us[1]); s2 += h2f(p.us[2]); s3 += h2f(p.us[3]);
  }
  union { u16 us[4]; unsigned long long ll; } u;
  u.us[0] = f2h(s0); u.us[1] = f2h(s1); u.us[2] = f2h(s2); u.us[3] = f2h(s3);
  ((unsigned long long*)MG)[i] = u.ll;
}

// ---------------- 256x(NH*128) NT GEMM (proven R15 structure) + T1 swizzle ----
// CMODE: 0=fp32 C, 3=fp16 C (bz-strided), 5=dual: n<1024 -> fp16 Tb[m*1024+n];
// n>=1024 -> transposed fp16 VWo (=Cv+8388608): [b=m>>11][d=n-1024][t=m&2047].
// QUAD: B-half selected by m-half (Bb += (by>>2)*1024*ldb).
template<int CMODE, bool BIAS, int NH, int FT, bool QUAD>
__global__ __launch_bounds__(512, 2) void gemmK(const u16* __restrict__ A,
                                                const u16* __restrict__ B,
                                                void* __restrict__ Cv,
                                                const float* __restrict__ bias,
                                                int K, int lda, int ldb, int ldc,
                                                long bsA, long bsB, long bsC,
                                                float alpha)
{
  __shared__ u16 sm[65536];
  const int gx = gridDim.x, gy = gridDim.y;
  const int nb = gx * gy * gridDim.z;
  const int bid0 = blockIdx.x + gx * (blockIdx.y + gy * blockIdx.z);
  const int nsw = (bid0 & 7) * (nb >> 3) + (bid0 >> 3);
  const int bx = nsw % gx, by = (nsw / gx) % gy, bz = nsw / (gx * gy);

  const u16* Ab = A + (long)bz * bsA;
  const u16* Bb = B + (long)bz * bsB;
  if constexpr (QUAD) Bb += (long)(by >> 2) * 1024 * ldb;
  const int m0 = by * 256, n0 = bx * (NH * 128);
  const int tid = threadIdx.x, lane = tid & 63, w = tid >> 6;
  const int wmr = w >> 2, wnr = w & 3;
  const int fr = lane & 15, ko = lane >> 4;

  f32x4 acc[8][2 * NH] = {};
  bf16x8 afA[8], afB[8], bfA[4], bfB[4];

  const u16* aP0 = sm + wmr * 8192 + fr * 64 + (((0 + ko) ^ (fr & 7)) * 8);
  const u16* aP1 = sm + wmr * 8192 + fr * 64 + (((4 + ko) ^ (fr & 7)) * 8);
  const u16* bP0 = sm + 32768 + wnr * (NH * 32) * 64 + fr * 64 + (((0 + ko) ^ (fr & 7)) * 8);
  const u16* bP1 = sm + 32768 + wnr * (NH * 32) * 64 + fr * 64 + (((4 + ko) ^ (fr & 7)) * 8);

#define LDAf(dst, D, MH)                                                        \
  { _Pragma("unroll") for (int mi = 0; mi < 4; ++mi) {                          \
      dst[mi * 2 + 0] = *(const bf16x8*)(aP0 + (D) * 16384 + (MH) * 4096 + mi * 1024); \
      dst[mi * 2 + 1] = *(const bf16x8*)(aP1 + (D) * 16384 + (MH) * 4096 + mi * 1024); } }
#define LDBf(dst, D, NHh)                                                       \
  { _Pragma("unroll") for (int ni = 0; ni < 2; ++ni) {                          \
      dst[ni * 2 + 0] = *(const bf16x8*)(bP0 + (D) * 16384 + (NHh) * 2048 + ni * 1024); \
      dst[ni * 2 + 1] = *(const bf16x8*)(bP1 + (D) * 16384 + (NHh) * 2048 + ni * 1024); } }

  const int lrow = w * 8 + (lane >> 3);
  const int c8 = ((lane & 7) ^ (lane >> 3)) * 8;
  const long dA = (long)lda * 64, dB = (long)ldb * 64;
  const u16* pA00 = Ab + (long)(m0 + lrow) * lda + c8;
  const u16* pA01 = pA00 + dA;
  const u16* pA10 = pA00 + 2 * dA;
  const u16* pA11 = pA00 + 3 * dA;
  const u16* pB00 = Bb + (long)(n0 + lrow) * ldb + c8;
  const u16* pB01 = pB00 + dB;
  const u16* pB10 = pB00 + 2 * dB;                           // NH==2 only
  const u16* pB11 = pB00 + 3 * dB;
  u16* dstB = sm + w * 512;

#define STG(ptr, CONSTOFF)                                                      \
  __builtin_amdgcn_global_load_lds((g_void*)(ptr), (lds_void*)(dstB + (CONSTOFF)), 16, 0, 0);
#define STG_A(D) { STG(pA00, (D)*16384 + 0)        STG(pA01, (D)*16384 + 4096)  \
                   STG(pA10, (D)*16384 + 8192)     STG(pA11, (D)*16384 + 12288) \
                   pA00 += 64; pA01 += 64; pA10 += 64; pA11 += 64; }
#define STG_B2(D) { STG(pB00, 32768 + (D)*16384 + 0)    STG(pB01, 32768 + (D)*16384 + 4096)  \
                    STG(pB10, 32768 + (D)*16384 + 8192) STG(pB11, 32768 + (D)*16384 + 12288) \
                    pB00 += 64; pB01 += 64; pB10 += 64; pB11 += 64; }
#define STG_B1(D) { STG(pB00, 32768 + (D)*16384 + 0)    STG(pB01, 32768 + (D)*16384 + 4096)  \
                    pB00 += 64; pB01 += 64; }

  auto MM = [&](const bf16x8* af, const bf16x8* bf, int mb, int nb2) {
    __builtin_amdgcn_s_setprio(1);
#pragma unroll
    for (int mi = 0; mi < 4; ++mi)
#pragma unroll
      for (int ni = 0; ni < 2; ++ni)
#pragma unroll
        for (int kk = 0; kk < 2; ++kk)
          acc[mb + mi][nb2 + ni] = __builtin_amdgcn_mfma_f32_16x16x32_f16(
              __builtin_bit_cast(f16x8, af[mi * 2 + kk]),
              __builtin_bit_cast(f16x8, bf[ni * 2 + kk]),
              acc[mb + mi][nb2 + ni], 0, 0, 0);
    __builtin_amdgcn_s_setprio(0);
  };

#define KTILE2(D, SEN)                                                          \
  { LDAf(afA, D, 0) LDBf(bfA, D, 0)                                             \
    if (SEN) { STG_A(D ^ 1) }                                                   \
    MM(afA, bfA, 0, 0);                                                         \
    LDBf(bfB, D, 1)                                                             \
    if (SEN) { STG_B2(D ^ 1) }                                                  \
    MM(afA, bfB, 0, 2);                                                         \
    LDAf(afB, D, 1)                                                             \
    MM(afB, bfB, 4, 2);                                                         \
    MM(afB, bfA, 4, 0);                                                         \
    asm volatile("s_waitcnt vmcnt(0)" ::: "memory");                            \
    asm volatile("s_barrier" ::: "memory"); }
#define KTILE1(D, SEN)                                                          \
  { LDAf(afA, D, 0) LDBf(bfA, D, 0)                                             \
    if (SEN) { STG_A(D ^ 1) }                                                   \
    MM(afA, bfA, 0, 0);                                                         \
    LDAf(afB, D, 1)                                                             \
    if (SEN) { STG_B1(D ^ 1) }                                                  \
    MM(afB, bfA, 4, 0);                                                         \
    asm volatile("s_waitcnt vmcnt(0)" ::: "memory");                            \
    asm volatile("s_barrier" ::: "memory"); }

  const int nt = K >> 6, niter = nt >> 1;

  STG_A(0)
  if constexpr (NH == 2) { STG_B2(0) } else { STG_B1(0) }
  asm volatile("s_waitcnt vmcnt(0)" ::: "memory");
  asm volatile("s_barrier" ::: "memory");

  for (int j = 0; j < niter; ++j) {
    const bool pre = (j + 1 < niter);
    if constexpr (NH == 2) {
      KTILE2(0, true)
      KTILE2(1, pre)
    } else {
      KTILE1(0, true)
      KTILE1(1, pre)
    }
  }

  // epilogue: C/D frag layout col=lane&15, row=(lane>>4)*4+r  (m89-verified)
  const int col = lane & 15, rb = (lane >> 4) * 4;
#pragma unroll
  for (int mi = 0; mi < 8; ++mi) {
#pragma unroll
    for (int ni = 0; ni < 2 * NH; ++ni) {
      const int mg = m0 + wmr * 128 + mi * 16 + rb;
      const int ng = n0 + wnr * (NH * 32) + ni * 16 + col;
      if constexpr (CMODE == 5) {
        if (n0 < 1024) {                                   // T half: fp16 normal
          u16* Cc = (u16*)Cv;
#pragma unroll
          for (int r = 0; r < 4; ++r)
            Cc[(long)(mg + r) * 1024 + ng] = f2h(acc[mi][ni][r]);
        } else {                                           // VWo half: transposed
          u16* Vc = (u16*)Cv + 8388608;
          const long bb = mg >> 11;
          const int  t  = mg & 2047, d = ng - 1024;
          union { u16 us[4]; unsigned long long ll; } u;
#pragma unroll
          for (int r = 0; r < 4; ++r) u.us[r] = f2h(acc[mi][ni][r]);
          *(unsigned long long*)(Vc + bb * 2097152 + (long)d * 2048 + t) = u.ll;
        }
      } else {
        const float bvv = BIAS ? bias[ng] : 0.0f;
        if constexpr (CMODE == 3) {
          u16* Cc = (u16*)Cv + (long)bz * bsC;
#pragma unroll
          for (int r = 0; r < 4; ++r)
            Cc[(long)(mg + r) * ldc + ng] = f2h(acc[mi][ni][r] * alpha + bvv);
        } else {
          float* Cf = (float*)Cv + (long)bz * bsC;
#pragma unroll
          for (int r = 0; r < 4; ++r)
            Cf[(long)(mg + r) * ldc + ng] = acc[mi][ni][r] * alpha + bvv;
        }
      }
    }
  }
#undef LDAf
#undef LDBf
#undef STG
#undef STG_A
#undef STG_B2
#undef STG_B1
#undef KTILE2
#undef KTILE1
}

// ------- row softmax: fp16 S row + v-column-term -> fp16 P -------------------
__global__ __launch_bounds__(256) void softmax_v(const u16* __restrict__ Scb,
                                                 const float* __restrict__ vv,
                                                 u16* __restrict__ Pb) {
  const int tid = threadIdx.x;
  const long row = blockIdx.x;
  const long vb = (row >> 11) << 11;
  union { int4 v; u16 us[8]; } u;
  u.v = ((const int4*)(Scb + row * 2048))[tid];
  float f[8];
#pragma unroll
  for (int j = 0; j < 8; ++j)
    f[j] = h2f(u.us[j]) + 0.03125f * vv[vb + tid * 8 + j];
  float mx = f[0];
#pragma unroll
  for (int j = 1; j < 8; ++j) mx = fmaxf(mx, f[j]);
  __shared__ float red[8];
  const int lane = tid & 63, wid = tid >> 6;
#pragma unroll
  for (int off = 32; off; off >>= 1) mx = fmaxf(mx, __shfl_down(mx, off));
  if (!lane) red[wid] = mx;
  __syncthreads();
  mx = fmaxf(fmaxf(red[0], red[1]), fmaxf(red[2], red[3]));
  float e[8], s = 0.f;
#pragma unroll
  for (int j = 0; j < 8; ++j) { e[j] = __expf(f[j] - mx); s += e[j]; }
#pragma unroll
  for (int off = 32; off; off >>= 1) s += __shfl_down(s, off);
  if (!lane) red[4 + wid] = s;
  __syncthreads();
  s = red[4] + red[5] + red[6] + red[7];
  const float inv = 1.0f / s;
  union { u16 us[8]; int4 v; } o;
#pragma unroll
  for (int j = 0; j < 8; ++j) o.us[j] = f2h(e[j] * inv);
  ((int4*)(Pb + row * 2048))[tid] = o.v;
}

extern "C" void kernel_launch(void* const* d_in, const int* in_sizes, int n_in,
                              void* d_out, int out_size, void* d_ws, size_t ws_size,
                              hipStream_t stream) {
  const float* X  = (const float*)d_in[0];
  const float* Wq = (const float*)d_in[1];
  const float* bq = (const float*)d_in[2];
  const float* Wk = (const float*)d_in[3];
  const float* Wv = (const float*)d_in[5];
  const float* bv = (const float*)d_in[6];
  const float* Wo = (const float*)d_in[7];
  const float* bo = (const float*)d_in[8];
  float* out = (float*)d_out;

  char* w = (char*)d_ws;
  u16* Xh   = (u16*)w; w += (size_t)8192 * 1024 * 2;
  u16* WA   = (u16*)w; w += (size_t)2048 * 2048 * 2;   // [Wkt ; Woh]
  u16* WB   = (u16*)w; w += (size_t)2048 * 2048 * 2;   // [Wqt ; Wvt]
  u16* MG   = (u16*)w; w += (size_t)2048 * 1024 * 2;   // [MT ; G] fp16
  u16* Tb   = (u16*)w; w += (size_t)8192 * 1024 * 2;   // fp16 T (VWo follows)
  u16* VWo  = (u16*)w; w += (size_t)4096 * 2048 * 2;   // fp16 [4][1024 d][2048 t]
  u16* Scb  = (u16*)w; w += (size_t)8192 * 2048 * 2;   // fp16 scores
  u16* Pb   = (u16*)w; w += (size_t)8192 * 2048 * 2;   // fp16 P
  float* wv = (float*)w; w += (size_t)1024 * 4;        // Wk^T bq
  float* vv = (float*)w; w += (size_t)8192 * 4;        // X wv
  float* bF = (float*)w; w += (size_t)1024 * 4;        // Wo bv + bo
  u16* Pp   = (u16*)w; w += (size_t)8 * 2048 * 1024 * 2;  // fp16 QUAD partials
  if ((size_t)(w - (char*)d_ws) > ws_size) return;
  (void)VWo;

  cvt_txp<<<16384, 256, 0, stream>>>(X, Wo, Wq, Wk, Wv, Xh, WA, WB);
  wvk2<<<512, 256, 0, stream>>>(WA, bq, bv, bo, wv, bF);
  vck<<<2048, 256, 0, stream>>>(Xh, wv, vv);

  // QUAD weight products -> fp16 partials (CMODE=3, bz-strided chunks)
  gemmK<3, false, 2, 1, true><<<dim3(4, 8, 8), 512, 0, stream>>>(WA, WB, Pp, nullptr,
      256, 2048, 2048, 1024, 256, 256, 2097152, 1.0f);
  redMG<<<2048, 256, 0, stream>>>(Pp, MG);

  // merged T | VWo: A=Xh, B=[MT;G], M=8192, N=2048, K=1024
  gemmK<5, false, 2, 1, false><<<dim3(8, 32, 1), 512, 0, stream>>>(Xh, MG, Tb, nullptr,
      1024, 1024, 1024, 1024, 0, 0, 0, 1.0f);

  // S = (T @ Xh^T)/32 per batch: M=2048, N=2048, K=1024 (fp16 out)
  gemmK<3, false, 2, 1, false><<<dim3(8, 8, 4), 512, 0, stream>>>(Tb, Xh, Scb, nullptr,
      1024, 1024, 1024, 2048, 2097152, 2097152, 4194304, 0.03125f);

  softmax_v<<<8192, 256, 0, stream>>>(Scb, vv, Pb);

  // out[b][s][d] = sum_t P[b][s][t]*VWo[b][d][t] + bF[d] : M=2048, N=1024, K=2048
  gemmK<0, true, 1, 1, false><<<dim3(8, 8, 4), 512, 0, stream>>>(Pb, Tb + 8388608, out, bF,
      2048, 2048, 2048, 1024, 4194304, 2097152, 2097152, 1.0f);
}